// Round 1
// baseline (341.072 us; speedup 1.0000x reference)
//
#include <hip/hip_runtime.h>
#include <hip/hip_bf16.h>

typedef __attribute__((ext_vector_type(8))) __bf16 bf16x8;
typedef __attribute__((ext_vector_type(4))) __bf16 bf16x4;
typedef __attribute__((ext_vector_type(4))) float  f32x4;

#define S_LEN 2048
#define D_DIM 1024
#define NH    16
#define GK    1024
#define GN    1024

// async global->LDS, 16B per lane; HW scatters to wave-uniform-base + lane*16
__device__ __forceinline__ void gld_lds16(const void* g, void* l) {
  __builtin_amdgcn_global_load_lds(
      (const __attribute__((address_space(1))) unsigned int*)g,
      (__attribute__((address_space(3))) unsigned int*)l, 16, 0, 0);
}

// ---------------- fp32 -> bf16 cast ----------------
__global__ __launch_bounds__(256) void cast_f32_bf16(
    const float* __restrict__ src, __bf16* __restrict__ dst, int n4)
{
  int i = blockIdx.x * 256 + threadIdx.x;
  if (i < n4) {
    float4 v = ((const float4*)src)[i];
    bf16x4 o = { (__bf16)v.x, (__bf16)v.y, (__bf16)v.z, (__bf16)v.w };
    ((bf16x4*)dst)[i] = o;
  }
}

// ---------------- GEMM: C[m][n] = sum_k A[m][k]*W[n][k]  (both row-major, K contig)
// m97 recipe: 128x128 tile, BK=32, global_load_lds w16, 16x16x32 bf16 MFMA,
// 4 waves in 2x2, 4x4 accs each. XOR chunk swizzle kills LDS bank conflicts.
__global__ __launch_bounds__(256) void gemm_bt(
    const __bf16* __restrict__ A,
    const __bf16* __restrict__ W0, const __bf16* __restrict__ W1, const __bf16* __restrict__ W2,
    float* __restrict__ C0, float* __restrict__ C1, float* __restrict__ C2)
{
  const __bf16* Wm = (blockIdx.z == 0) ? W0 : (blockIdx.z == 1) ? W1 : W2;
  float*        C  = (blockIdx.z == 0) ? C0 : (blockIdx.z == 1) ? C1 : C2;

  __shared__ __align__(16) __bf16 As[128 * 32];
  __shared__ __align__(16) __bf16 Bs[128 * 32];

  const int tid  = threadIdx.x;
  const int lane = tid & 63;
  const int w    = tid >> 6;
  const int wr   = w >> 1, wc = w & 1;
  const int lm   = lane & 15, qd = lane >> 4;
  const int m0 = blockIdx.y * 128, n0 = blockIdx.x * 128;

  // staging: 512 16B-chunks per tile; each thread 2 chunks; row = c>>2 (4 chunks/row)
  // LDS pos (r, cpos) holds global chunk cpos ^ s(r), s(r) = (r&3)^((r>>2)&1)
  const int c0 = tid, c1 = 256 + tid;
  const int r0 = c0 >> 2, r1 = c1 >> 2;
  const int g0 = ((c0 & 3) ^ (r0 & 3) ^ ((r0 >> 2) & 1)) * 8;
  const int g1 = ((c1 & 3) ^ (r1 & 3) ^ ((r1 >> 2) & 1)) * 8;
  const __bf16* a0p = A  + (size_t)(m0 + r0) * GK + g0;
  const __bf16* a1p = A  + (size_t)(m0 + r1) * GK + g1;
  const __bf16* b0p = Wm + (size_t)(n0 + r0) * GK + g0;
  const __bf16* b1p = Wm + (size_t)(n0 + r1) * GK + g1;

  // frag read: row R has s(R) = (lm&3)^((lm>>2)&1) (R = 16*base + lm)
  const int cp = (qd ^ (lm & 3) ^ ((lm >> 2) & 1)) * 8;

  f32x4 zero = {0.f, 0.f, 0.f, 0.f};
  f32x4 acc[4][4];
  #pragma unroll
  for (int i = 0; i < 4; i++)
    #pragma unroll
    for (int j = 0; j < 4; j++) acc[i][j] = zero;

  for (int k0 = 0; k0 < GK; k0 += 32) {
    gld_lds16(a0p + k0, &As[c0 * 8]);
    gld_lds16(a1p + k0, &As[c1 * 8]);
    gld_lds16(b0p + k0, &Bs[c0 * 8]);
    gld_lds16(b1p + k0, &Bs[c1 * 8]);
    __syncthreads();
    bf16x8 af[4], bfv[4];
    #pragma unroll
    for (int i = 0; i < 4; i++) af[i]  = *(const bf16x8*)&As[(wr * 64 + i * 16 + lm) * 32 + cp];
    #pragma unroll
    for (int j = 0; j < 4; j++) bfv[j] = *(const bf16x8*)&Bs[(wc * 64 + j * 16 + lm) * 32 + cp];
    #pragma unroll
    for (int i = 0; i < 4; i++)
      #pragma unroll
      for (int j = 0; j < 4; j++)
        acc[i][j] = __builtin_amdgcn_mfma_f32_16x16x32_bf16(af[i], bfv[j], acc[i][j], 0, 0, 0);
    __syncthreads();
  }

  #pragma unroll
  for (int i = 0; i < 4; i++) {
    const int row = m0 + wr * 64 + i * 16 + qd * 4;   // C/D: row=(lane>>4)*4+reg, col=lane&15
    #pragma unroll
    for (int j = 0; j < 4; j++) {
      const int col = n0 + wc * 64 + j * 16 + lm;
      #pragma unroll
      for (int r = 0; r < 4; r++)
        C[(size_t)(row + r) * GN + col] = acc[i][j][r];
    }
  }
}

// ---------------- RMSNorm + RoPE + head split ----------------
// 1 block per token row (b*S+s). Qh/Kh/Vh: [bh][s][64] bf16
__global__ __launch_bounds__(256) void norm_rope(
    const float* __restrict__ Qf, const float* __restrict__ Kf, const float* __restrict__ Vf,
    const float* __restrict__ gain, const int* __restrict__ positions,
    const int* __restrict__ theta_p,
    __bf16* __restrict__ Qh, __bf16* __restrict__ Kh, __bf16* __restrict__ Vh)
{
  const int row = blockIdx.x;             // b*S + s
  const int s = row & (S_LEN - 1), b = row >> 11;
  const int t = threadIdx.x, d0 = t * 4;

  const float4 q = *(const float4*)(Qf + (size_t)row * D_DIM + d0);
  const float4 k = *(const float4*)(Kf + (size_t)row * D_DIM + d0);
  const float4 v = *(const float4*)(Vf + (size_t)row * D_DIM + d0);

  float sq = q.x * q.x + q.y * q.y + q.z * q.z + q.w * q.w;
  float sk = k.x * k.x + k.y * k.y + k.z * k.z + k.w * k.w;
  #pragma unroll
  for (int off = 32; off; off >>= 1) { sq += __shfl_xor(sq, off); sk += __shfl_xor(sk, off); }
  __shared__ float red[8];
  const int lane = t & 63, wv = t >> 6;
  if (lane == 0) { red[wv] = sq; red[4 + wv] = sk; }
  __syncthreads();
  sq = red[0] + red[1] + red[2] + red[3];
  sk = red[4] + red[5] + red[6] + red[7];
  const float invq = rsqrtf(sq * (1.0f / 1024.0f) + 1e-5f);
  const float invk = rsqrtf(sk * (1.0f / 1024.0f) + 1e-5f);

  const float4 g = *(const float4*)(gain + d0);
  const float qn0 = q.x * invq * g.x, qn1 = q.y * invq * g.y;
  const float qn2 = q.z * invq * g.z, qn3 = q.w * invq * g.w;
  const float kn0 = k.x * invk * g.x, kn1 = k.y * invk * g.y;
  const float kn2 = k.z * invk * g.z, kn3 = k.w * invk * g.w;

  const float pos = (float)positions[s];
  const float th  = (float)theta_p[0];
  const int idx = d0 & 63, h = d0 >> 6, p0 = idx >> 1;
  const float f0 = powf(th, -(float)p0 * (1.0f / 32.0f));
  const float f1 = powf(th, -(float)(p0 + 1) * (1.0f / 32.0f));
  float s0, cc0, s1, cc1;
  sincosf(pos * f0, &s0, &cc0);
  sincosf(pos * f1, &s1, &cc1);

  const float qe0 = qn0 * cc0 - qn1 * s0, qo0 = qn1 * cc0 + qn0 * s0;
  const float qe1 = qn2 * cc1 - qn3 * s1, qo1 = qn3 * cc1 + qn2 * s1;
  const float ke0 = kn0 * cc0 - kn1 * s0, ko0 = kn1 * cc0 + kn0 * s0;
  const float ke1 = kn2 * cc1 - kn3 * s1, ko1 = kn3 * cc1 + kn2 * s1;

  const size_t obase = ((size_t)((b * NH + h) * S_LEN + s)) * 64 + idx;
  bf16x4 qo = { (__bf16)qe0, (__bf16)qo0, (__bf16)qe1, (__bf16)qo1 };
  bf16x4 ko = { (__bf16)ke0, (__bf16)ko0, (__bf16)ke1, (__bf16)ko1 };
  bf16x4 vo = { (__bf16)v.x, (__bf16)v.y, (__bf16)v.z, (__bf16)v.w };
  *(bf16x4*)(Qh + obase) = qo;
  *(bf16x4*)(Kh + obase) = ko;
  *(bf16x4*)(Vh + obase) = vo;
}

// ---------------- V transpose per head: [bh][s][64] -> [bh][64][s] ----------------
__global__ __launch_bounds__(256) void transpose_v(
    const __bf16* __restrict__ Vh, __bf16* __restrict__ Vt)
{
  __shared__ __bf16 tile[64][65];
  const int bh = blockIdx.y;
  const int s0 = blockIdx.x * 64;
  const int t = threadIdx.x;
  const int r = t >> 2, cb = (t & 3) * 16;
  const __bf16* src = Vh + ((size_t)(bh * S_LEN + s0 + r)) * 64 + cb;
  #pragma unroll
  for (int i = 0; i < 4; i++) {
    bf16x4 v = *(const bf16x4*)(src + i * 4);
    #pragma unroll
    for (int j = 0; j < 4; j++) tile[r][cb + i * 4 + j] = v[j];
  }
  __syncthreads();
  const int d = t >> 2, sb = (t & 3) * 16;
  __bf16* dst = Vt + ((size_t)bh * 64 + d) * S_LEN + s0 + sb;
  #pragma unroll
  for (int i = 0; i < 4; i++) {
    const int sl = sb + i * 4;
    bf16x4 o = { tile[sl][d], tile[sl + 1][d], tile[sl + 2][d], tile[sl + 3][d] };
    *(bf16x4*)(dst + i * 4) = o;
  }
}

// ---------------- causal flash attention ----------------
// grid (32 q-tiles, 32 bh), 256 thr. Wave w owns Q rows q0+16w..+15.
// K-tile/V-tile 64x64 bf16 in LDS (XOR-swizzled, staged via global_load_lds).
// P C-layout -> A-layout via per-wave LDS scratch (stride 72 = 2-way banks).
__global__ __launch_bounds__(256) void attn_fwd(
    const __bf16* __restrict__ Qh, const __bf16* __restrict__ Kh,
    const __bf16* __restrict__ Vt, __bf16* __restrict__ Ob)
{
  const int bh = blockIdx.y;
  const int qt = blockIdx.x;
  const int q0 = qt * 64;
  const int tid = threadIdx.x, lane = tid & 63, w = tid >> 6;
  const int lm = lane & 15, qd = lane >> 4;

  __shared__ __align__(16) __bf16 smem[4096 + 4096 + 4 * 1152];
  __bf16* Ks = smem;
  __bf16* Vs = smem + 4096;
  __bf16* Pw = smem + 8192 + w * 1152;

  const int qrow = q0 + w * 16 + lm;
  const size_t qoff = ((size_t)bh * S_LEN + qrow) * 64;
  const bf16x8 aq0 = *(const bf16x8*)(Qh + qoff + qd * 8);
  const bf16x8 aq1 = *(const bf16x8*)(Qh + qoff + 32 + qd * 8);

  float m[4], l[4];
  f32x4 zero = {0.f, 0.f, 0.f, 0.f};
  f32x4 o[4];
  #pragma unroll
  for (int r = 0; r < 4; r++) { m[r] = -1e30f; l[r] = 0.f; }
  #pragma unroll
  for (int jb = 0; jb < 4; jb++) o[jb] = zero;

  const __bf16* Kb = Kh + (size_t)bh * S_LEN * 64;
  const __bf16* Vb = Vt + (size_t)bh * 64 * S_LEN;
  // staging: 512 chunks/tile, 8 chunks/row; LDS (r,cpos) <- global chunk cpos^(r&7)
  const int c0 = tid, c1 = 256 + tid;
  const int kr0 = c0 >> 3, kr1 = c1 >> 3;
  const int kg0 = ((c0 & 7) ^ (kr0 & 7)) * 8;
  const int kg1 = ((c1 & 7) ^ (kr1 & 7)) * 8;
  const int cpA = (qd ^ (lm & 7)) * 8;   // frag chunk for k-half 0
  const int cpB = cpA ^ 32;              // k-half 1 (chunk+4)

  const int rowg = q0 + w * 16 + qd * 4; // first of this lane's 4 rows

  for (int kt = 0; kt <= qt; kt++) {
    const int k0 = kt * 64;
    gld_lds16(Kb + (size_t)(k0 + kr0) * 64 + kg0, &Ks[c0 * 8]);
    gld_lds16(Kb + (size_t)(k0 + kr1) * 64 + kg1, &Ks[c1 * 8]);
    gld_lds16(Vb + (size_t)kr0 * S_LEN + k0 + kg0, &Vs[c0 * 8]);
    gld_lds16(Vb + (size_t)kr1 * S_LEN + k0 + kg1, &Vs[c1 * 8]);
    __syncthreads();

    // S = Q K^T / 8, causal-masked
    float p[4][4];
    #pragma unroll
    for (int kb = 0; kb < 4; kb++) {
      const int krow = (kb * 16 + lm) * 64;
      const bf16x8 bk0 = *(const bf16x8*)&Ks[krow + cpA];
      const bf16x8 bk1 = *(const bf16x8*)&Ks[krow + cpB];
      f32x4 sc = zero;
      sc = __builtin_amdgcn_mfma_f32_16x16x32_bf16(aq0, bk0, sc, 0, 0, 0);
      sc = __builtin_amdgcn_mfma_f32_16x16x32_bf16(aq1, bk1, sc, 0, 0, 0);
      const int colg = k0 + kb * 16 + lm;
      #pragma unroll
      for (int r = 0; r < 4; r++)
        p[kb][r] = (colg <= rowg + r) ? sc[r] * 0.125f : -1e30f;
    }

    // online softmax (row spread over 16 lanes of the quad)
    #pragma unroll
    for (int r = 0; r < 4; r++) {
      float mx = fmaxf(fmaxf(p[0][r], p[1][r]), fmaxf(p[2][r], p[3][r]));
      #pragma unroll
      for (int off = 8; off; off >>= 1) mx = fmaxf(mx, __shfl_xor(mx, off));
      const float mn = fmaxf(m[r], mx);
      const float alpha = expf(m[r] - mn);
      float rs = 0.f;
      #pragma unroll
      for (int kb = 0; kb < 4; kb++) { p[kb][r] = expf(p[kb][r] - mn); rs += p[kb][r]; }
      #pragma unroll
      for (int off = 8; off; off >>= 1) rs += __shfl_xor(rs, off);
      l[r] = l[r] * alpha + rs;
      m[r] = mn;
      #pragma unroll
      for (int jb = 0; jb < 4; jb++) o[jb][r] *= alpha;
    }

    // P: C-layout -> LDS (stride 72) -> A-layout frags
    #pragma unroll
    for (int kb = 0; kb < 4; kb++)
      #pragma unroll
      for (int r = 0; r < 4; r++)
        Pw[(qd * 4 + r) * 72 + kb * 16 + lm] = (__bf16)p[kb][r];

    const bf16x8 ap0 = *(const bf16x8*)&Pw[lm * 72 + qd * 8];
    const bf16x8 ap1 = *(const bf16x8*)&Pw[lm * 72 + 32 + qd * 8];
    #pragma unroll
    for (int jb = 0; jb < 4; jb++) {
      const int vrow = (jb * 16 + lm) * 64;
      const bf16x8 bv0 = *(const bf16x8*)&Vs[vrow + cpA];
      const bf16x8 bv1 = *(const bf16x8*)&Vs[vrow + cpB];
      o[jb] = __builtin_amdgcn_mfma_f32_16x16x32_bf16(ap1, bv1,
              __builtin_amdgcn_mfma_f32_16x16x32_bf16(ap0, bv0, o[jb], 0, 0, 0), 0, 0, 0);
    }
    __syncthreads();
  }

  const int b = bh >> 4, h = bh & 15;
  #pragma unroll
  for (int r = 0; r < 4; r++) {
    const float inv = 1.0f / l[r];
    const size_t base = ((size_t)(b * S_LEN + rowg + r)) * D_DIM + h * 64;
    #pragma unroll
    for (int jb = 0; jb < 4; jb++)
      Ob[base + jb * 16 + lm] = (__bf16)(o[jb][r] * inv);
  }
}

extern "C" void kernel_launch(void* const* d_in, const int* in_sizes, int n_in,
                              void* d_out, int out_size, void* d_ws, size_t ws_size,
                              hipStream_t stream)
{
  (void)in_sizes; (void)n_in; (void)out_size; (void)ws_size;
  const float* x    = (const float*)d_in[0];
  const float* WQ   = (const float*)d_in[1];
  const float* WK   = (const float*)d_in[2];
  const float* WV   = (const float*)d_in[3];
  const float* WO   = (const float*)d_in[4];
  const float* gain = (const float*)d_in[5];
  const int* positions = (const int*)d_in[6];
  const int* theta     = (const int*)d_in[7];
  float* out = (float*)d_out;

  char* ws = (char*)d_ws;
  const size_t MB = 1024 * 1024;
  __bf16* xb  = (__bf16*)(ws + 0);        //  8 MB  x bf16 [4096][1024]
  __bf16* WQb = (__bf16*)(ws + 8  * MB);  //  2 MB
  __bf16* WKb = (__bf16*)(ws + 10 * MB);  //  2 MB
  __bf16* WVb = (__bf16*)(ws + 12 * MB);  //  2 MB
  __bf16* WOb = (__bf16*)(ws + 14 * MB);  //  2 MB
  float*  Qf  = (float*) (ws + 16 * MB);  // 16 MB  [4096][1024] fp32
  float*  Kf  = (float*) (ws + 32 * MB);  // 16 MB
  float*  Vf  = (float*) (ws + 48 * MB);  // 16 MB
  __bf16* Qh  = (__bf16*)(ws + 64 * MB);  //  8 MB  [bh][s][64]
  __bf16* Kh  = (__bf16*)(ws + 72 * MB);  //  8 MB
  __bf16* Vh  = (__bf16*)(ws + 80 * MB);  //  8 MB
  __bf16* Vt  = (__bf16*)(ws + 88 * MB);  //  8 MB  [bh][64][s]
  __bf16* Ob  = (__bf16*)(ws + 96 * MB);  //  8 MB  [b][s][1024]

  cast_f32_bf16<<<4096, 256, 0, stream>>>(x,  xb,  4 * 1024 * 1024 / 4);
  cast_f32_bf16<<<1024, 256, 0, stream>>>(WQ, WQb, 1024 * 1024 / 4);
  cast_f32_bf16<<<1024, 256, 0, stream>>>(WK, WKb, 1024 * 1024 / 4);
  cast_f32_bf16<<<1024, 256, 0, stream>>>(WV, WVb, 1024 * 1024 / 4);
  cast_f32_bf16<<<1024, 256, 0, stream>>>(WO, WOb, 1024 * 1024 / 4);

  gemm_bt<<<dim3(8, 32, 3), 256, 0, stream>>>(xb, WQb, WKb, WVb, Qf, Kf, Vf);
  norm_rope<<<4096, 256, 0, stream>>>(Qf, Kf, Vf, gain, positions, theta, Qh, Kh, Vh);
  transpose_v<<<dim3(32, 32), 256, 0, stream>>>(Vh, Vt);
  attn_fwd<<<dim3(32, 32), 256, 0, stream>>>(Qh, Kh, Vt, Ob);
  gemm_bt<<<dim3(8, 32, 1), 256, 0, stream>>>(Ob, WOb, WOb, WOb, out, out, out);
}

// Round 2
// 250.626 us; speedup vs baseline: 1.3609x; 1.3609x over previous
//
#include <hip/hip_runtime.h>
#include <hip/hip_bf16.h>

typedef __attribute__((ext_vector_type(8))) __bf16 bf16x8;
typedef __attribute__((ext_vector_type(4))) __bf16 bf16x4;
typedef __attribute__((ext_vector_type(4))) float  f32x4;

#define S_LEN 2048
#define D_DIM 1024
#define NH    16
#define GK    1024
#define GN    1024

__device__ __forceinline__ float fast_exp2(float x) {
#if __has_builtin(__builtin_amdgcn_exp2f)
  return __builtin_amdgcn_exp2f(x);
#else
  return exp2f(x);
#endif
}

// async global->LDS, 16B per lane; HW scatters to wave-uniform-base + lane*16
__device__ __forceinline__ void gld_lds16(const void* g, void* l) {
  __builtin_amdgcn_global_load_lds(
      (const __attribute__((address_space(1))) unsigned int*)g,
      (__attribute__((address_space(3))) unsigned int*)l, 16, 0, 0);
}

// ---------------- fused fp32 -> bf16 cast: x (1M float4) + 4 weights (256K float4 each)
__global__ __launch_bounds__(256) void cast_all(
    const float* __restrict__ x,  const float* __restrict__ wq, const float* __restrict__ wk,
    const float* __restrict__ wv, const float* __restrict__ wo,
    __bf16* __restrict__ xb, __bf16* __restrict__ wqb, __bf16* __restrict__ wkb,
    __bf16* __restrict__ wvb, __bf16* __restrict__ wob)
{
  const int i = blockIdx.x * 256 + threadIdx.x;      // 2M chunks total
  const float* s; __bf16* d; int off;
  if (i < (1 << 20)) { s = x; d = xb; off = i; }
  else {
    const int j = i - (1 << 20);
    const int r = j >> 18; off = j & ((1 << 18) - 1);
    s = (r == 0) ? wq : (r == 1) ? wk : (r == 2) ? wv : wo;
    d = (r == 0) ? wqb : (r == 1) ? wkb : (r == 2) ? wvb : wob;
  }
  float4 v = ((const float4*)s)[off];
  bf16x4 o = { (__bf16)v.x, (__bf16)v.y, (__bf16)v.z, (__bf16)v.w };
  ((bf16x4*)d)[off] = o;
}

// ---------------- GEMM: C[m][n] = sum_k A[m][k]*W[n][k]  (both row-major, K contig)
__global__ __launch_bounds__(256) void gemm_bt(
    const __bf16* __restrict__ A,
    const __bf16* __restrict__ W0, const __bf16* __restrict__ W1, const __bf16* __restrict__ W2,
    float* __restrict__ C0, float* __restrict__ C1, float* __restrict__ C2)
{
  const __bf16* Wm = (blockIdx.z == 0) ? W0 : (blockIdx.z == 1) ? W1 : W2;
  float*        C  = (blockIdx.z == 0) ? C0 : (blockIdx.z == 1) ? C1 : C2;

  __shared__ __align__(16) __bf16 As[128 * 32];
  __shared__ __align__(16) __bf16 Bs[128 * 32];

  const int tid  = threadIdx.x;
  const int lane = tid & 63;
  const int w    = tid >> 6;
  const int wr   = w >> 1, wc = w & 1;
  const int lm   = lane & 15, qd = lane >> 4;
  const int m0 = blockIdx.y * 128, n0 = blockIdx.x * 128;

  const int c0 = tid, c1 = 256 + tid;
  const int r0 = c0 >> 2, r1 = c1 >> 2;
  const int g0 = ((c0 & 3) ^ (r0 & 3) ^ ((r0 >> 2) & 1)) * 8;
  const int g1 = ((c1 & 3) ^ (r1 & 3) ^ ((r1 >> 2) & 1)) * 8;
  const __bf16* a0p = A  + (size_t)(m0 + r0) * GK + g0;
  const __bf16* a1p = A  + (size_t)(m0 + r1) * GK + g1;
  const __bf16* b0p = Wm + (size_t)(n0 + r0) * GK + g0;
  const __bf16* b1p = Wm + (size_t)(n0 + r1) * GK + g1;

  const int cp = (qd ^ (lm & 3) ^ ((lm >> 2) & 1)) * 8;

  f32x4 zero = {0.f, 0.f, 0.f, 0.f};
  f32x4 acc[4][4];
  #pragma unroll
  for (int i = 0; i < 4; i++)
    #pragma unroll
    for (int j = 0; j < 4; j++) acc[i][j] = zero;

  for (int k0 = 0; k0 < GK; k0 += 32) {
    gld_lds16(a0p + k0, &As[c0 * 8]);
    gld_lds16(a1p + k0, &As[c1 * 8]);
    gld_lds16(b0p + k0, &Bs[c0 * 8]);
    gld_lds16(b1p + k0, &Bs[c1 * 8]);
    __syncthreads();
    bf16x8 af[4], bfv[4];
    #pragma unroll
    for (int i = 0; i < 4; i++) af[i]  = *(const bf16x8*)&As[(wr * 64 + i * 16 + lm) * 32 + cp];
    #pragma unroll
    for (int j = 0; j < 4; j++) bfv[j] = *(const bf16x8*)&Bs[(wc * 64 + j * 16 + lm) * 32 + cp];
    #pragma unroll
    for (int i = 0; i < 4; i++)
      #pragma unroll
      for (int j = 0; j < 4; j++)
        acc[i][j] = __builtin_amdgcn_mfma_f32_16x16x32_bf16(af[i], bfv[j], acc[i][j], 0, 0, 0);
    __syncthreads();
  }

  #pragma unroll
  for (int i = 0; i < 4; i++) {
    const int row = m0 + wr * 64 + i * 16 + qd * 4;
    #pragma unroll
    for (int j = 0; j < 4; j++) {
      const int col = n0 + wc * 64 + j * 16 + lm;
      #pragma unroll
      for (int r = 0; r < 4; r++)
        C[(size_t)(row + r) * GN + col] = acc[i][j][r];
    }
  }
}

// ---------------- RMSNorm + RoPE + head split ----------------
__global__ __launch_bounds__(256) void norm_rope(
    const float* __restrict__ Qf, const float* __restrict__ Kf, const float* __restrict__ Vf,
    const float* __restrict__ gain, const int* __restrict__ positions,
    const int* __restrict__ theta_p,
    __bf16* __restrict__ Qh, __bf16* __restrict__ Kh, __bf16* __restrict__ Vh)
{
  const int row = blockIdx.x;             // b*S + s
  const int s = row & (S_LEN - 1), b = row >> 11;
  const int t = threadIdx.x, d0 = t * 4;

  const float4 q = *(const float4*)(Qf + (size_t)row * D_DIM + d0);
  const float4 k = *(const float4*)(Kf + (size_t)row * D_DIM + d0);
  const float4 v = *(const float4*)(Vf + (size_t)row * D_DIM + d0);

  float sq = q.x * q.x + q.y * q.y + q.z * q.z + q.w * q.w;
  float sk = k.x * k.x + k.y * k.y + k.z * k.z + k.w * k.w;
  #pragma unroll
  for (int off = 32; off; off >>= 1) { sq += __shfl_xor(sq, off); sk += __shfl_xor(sk, off); }
  __shared__ float red[8];
  const int lane = t & 63, wv = t >> 6;
  if (lane == 0) { red[wv] = sq; red[4 + wv] = sk; }
  __syncthreads();
  sq = red[0] + red[1] + red[2] + red[3];
  sk = red[4] + red[5] + red[6] + red[7];
  const float invq = rsqrtf(sq * (1.0f / 1024.0f) + 1e-5f);
  const float invk = rsqrtf(sk * (1.0f / 1024.0f) + 1e-5f);

  const float4 g = *(const float4*)(gain + d0);
  const float qn0 = q.x * invq * g.x, qn1 = q.y * invq * g.y;
  const float qn2 = q.z * invq * g.z, qn3 = q.w * invq * g.w;
  const float kn0 = k.x * invk * g.x, kn1 = k.y * invk * g.y;
  const float kn2 = k.z * invk * g.z, kn3 = k.w * invk * g.w;

  const float pos = (float)positions[s];
  const float th  = (float)theta_p[0];
  const int idx = d0 & 63, h = d0 >> 6, p0 = idx >> 1;
  const float lg32 = __log2f(th) * (1.0f / 32.0f);
  const float f0 = fast_exp2(-(float)p0 * lg32);
  const float f1 = fast_exp2(-(float)(p0 + 1) * lg32);
  float s0, cc0, s1, cc1;
  __sincosf(pos * f0, &s0, &cc0);
  __sincosf(pos * f1, &s1, &cc1);

  const float qe0 = qn0 * cc0 - qn1 * s0, qo0 = qn1 * cc0 + qn0 * s0;
  const float qe1 = qn2 * cc1 - qn3 * s1, qo1 = qn3 * cc1 + qn2 * s1;
  const float ke0 = kn0 * cc0 - kn1 * s0, ko0 = kn1 * cc0 + kn0 * s0;
  const float ke1 = kn2 * cc1 - kn3 * s1, ko1 = kn3 * cc1 + kn2 * s1;

  const size_t obase = ((size_t)((b * NH + h) * S_LEN + s)) * 64 + idx;
  bf16x4 qo = { (__bf16)qe0, (__bf16)qo0, (__bf16)qe1, (__bf16)qo1 };
  bf16x4 ko = { (__bf16)ke0, (__bf16)ko0, (__bf16)ke1, (__bf16)ko1 };
  bf16x4 vo = { (__bf16)v.x, (__bf16)v.y, (__bf16)v.z, (__bf16)v.w };
  *(bf16x4*)(Qh + obase) = qo;
  *(bf16x4*)(Kh + obase) = ko;
  *(bf16x4*)(Vh + obase) = vo;
}

// ---------------- V transpose per head: [bh][s][64] -> [bh][64][s] ----------------
__global__ __launch_bounds__(256) void transpose_v(
    const __bf16* __restrict__ Vh, __bf16* __restrict__ Vt)
{
  __shared__ __bf16 tile[64][65];
  const int bh = blockIdx.y;
  const int s0 = blockIdx.x * 64;
  const int t = threadIdx.x;
  const int r = t >> 2, cb = (t & 3) * 16;
  const __bf16* src = Vh + ((size_t)(bh * S_LEN + s0 + r)) * 64 + cb;
  #pragma unroll
  for (int i = 0; i < 4; i++) {
    bf16x4 v = *(const bf16x4*)(src + i * 4);
    #pragma unroll
    for (int j = 0; j < 4; j++) tile[r][cb + i * 4 + j] = v[j];
  }
  __syncthreads();
  const int d = t >> 2, sb = (t & 3) * 16;
  __bf16* dst = Vt + ((size_t)bh * 64 + d) * S_LEN + s0 + sb;
  #pragma unroll
  for (int i = 0; i < 4; i++) {
    const int sl = sb + i * 4;
    bf16x4 o = { tile[sl][d], tile[sl + 1][d], tile[sl + 2][d], tile[sl + 3][d] };
    *(bf16x4*)(dst + i * 4) = o;
  }
}

// ---------------- causal flash attention, balanced + double-buffered ----------------
// grid (16, 32). Block px handles q-tile px then q-tile 31-px: exactly 33 k-iters each.
// K/V tiles double-buffered; next tile staged right after the barrier so the vmcnt(0)
// drain at the following barrier comes after a full compute phase (latency hidden).
// Softmax in exp2 domain; per-lane partial l (no per-tile sum reduce); mask only diag.
__global__ __launch_bounds__(256) void attn_fwd(
    const __bf16* __restrict__ Qh, const __bf16* __restrict__ Kh,
    const __bf16* __restrict__ Vt, __bf16* __restrict__ Ob)
{
  const int bh = blockIdx.y;
  const int px = blockIdx.x;
  const int tid = threadIdx.x, lane = tid & 63, w = tid >> 6;
  const int lm = lane & 15, qd = lane >> 4;

  __shared__ __align__(16) __bf16 smem[2 * 4096 + 2 * 4096 + 4 * 1152];
  __bf16* Ks = smem;                 // [2][4096]
  __bf16* Vs = smem + 8192;          // [2][4096]
  __bf16* Pw = smem + 16384 + w * 1152;

  const int qtA = px, qtB = 31 - px;
  const int rowA = qtA * 64 + w * 16, rowB = qtB * 64 + w * 16;

  const size_t qbase = (size_t)bh * S_LEN * 64;
  const bf16x8 aqA0 = *(const bf16x8*)(Qh + qbase + (size_t)(rowA + lm) * 64 + qd * 8);
  const bf16x8 aqA1 = *(const bf16x8*)(Qh + qbase + (size_t)(rowA + lm) * 64 + 32 + qd * 8);
  const bf16x8 aqB0 = *(const bf16x8*)(Qh + qbase + (size_t)(rowB + lm) * 64 + qd * 8);
  const bf16x8 aqB1 = *(const bf16x8*)(Qh + qbase + (size_t)(rowB + lm) * 64 + 32 + qd * 8);

  const __bf16* Kb = Kh + (size_t)bh * S_LEN * 64;
  const __bf16* Vb = Vt + (size_t)bh * 64 * S_LEN;
  const int c0 = tid, c1 = 256 + tid;
  const int kr0 = c0 >> 3, kr1 = c1 >> 3;
  const int kg0 = ((c0 & 7) ^ (kr0 & 7)) * 8;
  const int kg1 = ((c1 & 7) ^ (kr1 & 7)) * 8;
  const int cpA = (qd ^ (lm & 7)) * 8;
  const int cpB = cpA ^ 32;

  auto stage = [&](int buf, int k0) {
    __bf16* Kd = Ks + buf * 4096;
    __bf16* Vd = Vs + buf * 4096;
    gld_lds16(Kb + (size_t)(k0 + kr0) * 64 + kg0, &Kd[c0 * 8]);
    gld_lds16(Kb + (size_t)(k0 + kr1) * 64 + kg1, &Kd[c1 * 8]);
    gld_lds16(Vb + (size_t)kr0 * S_LEN + k0 + kg0, &Vd[c0 * 8]);
    gld_lds16(Vb + (size_t)kr1 * S_LEN + k0 + kg1, &Vd[c1 * 8]);
  };

  const float SC2 = 0.125f * 1.44269504089f;   // 1/sqrt(64) * log2(e)
  f32x4 zero = {0.f, 0.f, 0.f, 0.f};
  float m[4], l[4];
  f32x4 o[4];

  stage(0, 0);                       // prologue: first tile of segment A

  const int b = bh >> 4, h = bh & 15;

  for (int it = 0; it < 33; ++it) {
    const int seg = (it > qtA);
    const int kt  = seg ? it - qtA - 1 : it;
    const int qt  = seg ? qtB : qtA;
    const int cur = it & 1;

    if (kt == 0) {
      #pragma unroll
      for (int r = 0; r < 4; r++) { m[r] = -1e30f; l[r] = 0.f; }
      #pragma unroll
      for (int jb = 0; jb < 4; jb++) o[jb] = zero;
    }

    __syncthreads();                 // buf[cur] staged; buf[cur^1] free to overwrite
    if (it + 1 < 33) {
      const int nkt = (it + 1 > qtA) ? it - qtA : it + 1;
      stage(cur ^ 1, nkt * 64);
    }

    const __bf16* Kc = Ks + cur * 4096;
    const __bf16* Vc = Vs + cur * 4096;
    const bf16x8 a0 = seg ? aqB0 : aqA0;
    const bf16x8 a1 = seg ? aqB1 : aqA1;
    const int rowg = (seg ? rowB : rowA) + qd * 4;
    const int k0 = kt * 64;

    // S = Q K^T (exp2 domain), masked only on the diagonal tile
    float p[4][4];
    const bool diag = (kt == qt);
    #pragma unroll
    for (int kb = 0; kb < 4; kb++) {
      const int krow = (kb * 16 + lm) * 64;
      const bf16x8 bk0 = *(const bf16x8*)&Kc[krow + cpA];
      const bf16x8 bk1 = *(const bf16x8*)&Kc[krow + cpB];
      f32x4 sc = zero;
      sc = __builtin_amdgcn_mfma_f32_16x16x32_bf16(a0, bk0, sc, 0, 0, 0);
      sc = __builtin_amdgcn_mfma_f32_16x16x32_bf16(a1, bk1, sc, 0, 0, 0);
      if (diag) {
        const int colg = k0 + kb * 16 + lm;
        #pragma unroll
        for (int r = 0; r < 4; r++)
          p[kb][r] = (colg <= rowg + r) ? sc[r] * SC2 : -1e30f;
      } else {
        #pragma unroll
        for (int r = 0; r < 4; r++) p[kb][r] = sc[r] * SC2;
      }
    }

    // online softmax: cross-lane max reduce; l stays per-lane partial
    #pragma unroll
    for (int r = 0; r < 4; r++) {
      float mx = fmaxf(fmaxf(p[0][r], p[1][r]), fmaxf(p[2][r], p[3][r]));
      #pragma unroll
      for (int off = 8; off; off >>= 1) mx = fmaxf(mx, __shfl_xor(mx, off));
      const float mn = fmaxf(m[r], mx);
      const float alpha = fast_exp2(m[r] - mn);
      float rs = 0.f;
      #pragma unroll
      for (int kb = 0; kb < 4; kb++) { p[kb][r] = fast_exp2(p[kb][r] - mn); rs += p[kb][r]; }
      l[r] = l[r] * alpha + rs;
      m[r] = mn;
      #pragma unroll
      for (int jb = 0; jb < 4; jb++) o[jb][r] *= alpha;
    }

    // P: C-layout -> LDS (stride 72) -> A-layout frags
    #pragma unroll
    for (int kb = 0; kb < 4; kb++)
      #pragma unroll
      for (int r = 0; r < 4; r++)
        Pw[(qd * 4 + r) * 72 + kb * 16 + lm] = (__bf16)p[kb][r];

    const bf16x8 ap0 = *(const bf16x8*)&Pw[lm * 72 + qd * 8];
    const bf16x8 ap1 = *(const bf16x8*)&Pw[lm * 72 + 32 + qd * 8];
    #pragma unroll
    for (int jb = 0; jb < 4; jb++) {
      const int vrow = (jb * 16 + lm) * 64;
      const bf16x8 bv0 = *(const bf16x8*)&Vc[vrow + cpA];
      const bf16x8 bv1 = *(const bf16x8*)&Vc[vrow + cpB];
      o[jb] = __builtin_amdgcn_mfma_f32_16x16x32_bf16(ap1, bv1,
              __builtin_amdgcn_mfma_f32_16x16x32_bf16(ap0, bv0, o[jb], 0, 0, 0), 0, 0, 0);
    }

    if (kt == qt) {                  // segment epilogue
      #pragma unroll
      for (int r = 0; r < 4; r++) {
        float lr = l[r];
        #pragma unroll
        for (int off = 8; off; off >>= 1) lr += __shfl_xor(lr, off);
        const float inv = 1.0f / lr;
        const size_t base = ((size_t)(b * S_LEN + rowg + r)) * D_DIM + h * 64;
        #pragma unroll
        for (int jb = 0; jb < 4; jb++)
          Ob[base + jb * 16 + lm] = (__bf16)(o[jb][r] * inv);
      }
    }
  }
}

extern "C" void kernel_launch(void* const* d_in, const int* in_sizes, int n_in,
                              void* d_out, int out_size, void* d_ws, size_t ws_size,
                              hipStream_t stream)
{
  (void)in_sizes; (void)n_in; (void)out_size; (void)ws_size;
  const float* x    = (const float*)d_in[0];
  const float* WQ   = (const float*)d_in[1];
  const float* WK   = (const float*)d_in[2];
  const float* WV   = (const float*)d_in[3];
  const float* WO   = (const float*)d_in[4];
  const float* gain = (const float*)d_in[5];
  const int* positions = (const int*)d_in[6];
  const int* theta     = (const int*)d_in[7];
  float* out = (float*)d_out;

  char* ws = (char*)d_ws;
  const size_t MB = 1024 * 1024;
  __bf16* xb  = (__bf16*)(ws + 0);        //  8 MB
  __bf16* WQb = (__bf16*)(ws + 8  * MB);  //  2 MB
  __bf16* WKb = (__bf16*)(ws + 10 * MB);  //  2 MB
  __bf16* WVb = (__bf16*)(ws + 12 * MB);  //  2 MB
  __bf16* WOb = (__bf16*)(ws + 14 * MB);  //  2 MB
  float*  Qf  = (float*) (ws + 16 * MB);  // 16 MB
  float*  Kf  = (float*) (ws + 32 * MB);  // 16 MB
  float*  Vf  = (float*) (ws + 48 * MB);  // 16 MB
  __bf16* Qh  = (__bf16*)(ws + 64 * MB);  //  8 MB  [bh][s][64]
  __bf16* Kh  = (__bf16*)(ws + 72 * MB);  //  8 MB
  __bf16* Vh  = (__bf16*)(ws + 80 * MB);  //  8 MB
  __bf16* Vt  = (__bf16*)(ws + 88 * MB);  //  8 MB  [bh][64][s]
  __bf16* Ob  = (__bf16*)(ws + 96 * MB);  //  8 MB  [b][s][1024]

  cast_all<<<8192, 256, 0, stream>>>(x, WQ, WK, WV, WO, xb, WQb, WKb, WVb, WOb);
  gemm_bt<<<dim3(8, 32, 3), 256, 0, stream>>>(xb, WQb, WKb, WVb, Qf, Kf, Vf);
  norm_rope<<<4096, 256, 0, stream>>>(Qf, Kf, Vf, gain, positions, theta, Qh, Kh, Vh);
  transpose_v<<<dim3(32, 32), 256, 0, stream>>>(Vh, Vt);
  attn_fwd<<<dim3(16, 32), 256, 0, stream>>>(Qh, Kh, Vt, Ob);
  gemm_bt<<<dim3(8, 32, 1), 256, 0, stream>>>(Ob, WOb, WOb, WOb, out, out, out);
}

// Round 3
// 228.311 us; speedup vs baseline: 1.4939x; 1.0977x over previous
//
#include <hip/hip_runtime.h>
#include <hip/hip_bf16.h>

typedef __attribute__((ext_vector_type(8))) __bf16 bf16x8;
typedef __attribute__((ext_vector_type(4))) __bf16 bf16x4;
typedef __attribute__((ext_vector_type(4))) float  f32x4;

#define S_LEN 2048
#define D_DIM 1024
#define NH    16
#define GK    1024
#define GN    1024

__device__ __forceinline__ float fast_exp2(float x) {
#if __has_builtin(__builtin_amdgcn_exp2f)
  return __builtin_amdgcn_exp2f(x);
#else
  return exp2f(x);
#endif
}

// async global->LDS, 16B per lane; HW scatters to wave-uniform-base + lane*16
__device__ __forceinline__ void gld_lds16(const void* g, void* l) {
  __builtin_amdgcn_global_load_lds(
      (const __attribute__((address_space(1))) unsigned int*)g,
      (__attribute__((address_space(3))) unsigned int*)l, 16, 0, 0);
}

// ---------------- fused fp32 -> bf16 cast: x (1M float4) + 4 weights (256K float4 each)
__global__ __launch_bounds__(256) void cast_all(
    const float* __restrict__ x,  const float* __restrict__ wq, const float* __restrict__ wk,
    const float* __restrict__ wv, const float* __restrict__ wo,
    __bf16* __restrict__ xb, __bf16* __restrict__ wqb, __bf16* __restrict__ wkb,
    __bf16* __restrict__ wvb, __bf16* __restrict__ wob)
{
  const int i = blockIdx.x * 256 + threadIdx.x;      // 2M chunks total
  const float* s; __bf16* d; int off;
  if (i < (1 << 20)) { s = x; d = xb; off = i; }
  else {
    const int j = i - (1 << 20);
    const int r = j >> 18; off = j & ((1 << 18) - 1);
    s = (r == 0) ? wq : (r == 1) ? wk : (r == 2) ? wv : wo;
    d = (r == 0) ? wqb : (r == 1) ? wkb : (r == 2) ? wvb : wob;
  }
  float4 v = ((const float4*)s)[off];
  bf16x4 o = { (__bf16)v.x, (__bf16)v.y, (__bf16)v.z, (__bf16)v.w };
  ((bf16x4*)d)[off] = o;
}

// ---------------- GEMM: C[m][n] = sum_k A[m][k]*W[n][k]  (both row-major, K contig)
// z=0/1: fp32 C row-major (Q/K, or the final output). z=2: bf16 direct to Vt [bh][d][s]
// (V needs no norm/rope — epilogue does the head-split + transpose for free: the 4
// C/D regs of an acc are 4 consecutive tokens at one vdim = contiguous 8B in Vt).
__global__ __launch_bounds__(256) void gemm_bt(
    const __bf16* __restrict__ A,
    const __bf16* __restrict__ W0, const __bf16* __restrict__ W1, const __bf16* __restrict__ W2,
    float* __restrict__ C0, float* __restrict__ C1, __bf16* __restrict__ VtOut)
{
  const int mode = blockIdx.z;
  const __bf16* Wm = (mode == 0) ? W0 : (mode == 1) ? W1 : W2;

  __shared__ __align__(16) __bf16 As[128 * 32];
  __shared__ __align__(16) __bf16 Bs[128 * 32];

  const int tid  = threadIdx.x;
  const int lane = tid & 63;
  const int w    = tid >> 6;
  const int wr   = w >> 1, wc = w & 1;
  const int lm   = lane & 15, qd = lane >> 4;
  const int m0 = blockIdx.y * 128, n0 = blockIdx.x * 128;

  const int c0 = tid, c1 = 256 + tid;
  const int r0 = c0 >> 2, r1 = c1 >> 2;
  const int g0 = ((c0 & 3) ^ (r0 & 3) ^ ((r0 >> 2) & 1)) * 8;
  const int g1 = ((c1 & 3) ^ (r1 & 3) ^ ((r1 >> 2) & 1)) * 8;
  const __bf16* a0p = A  + (size_t)(m0 + r0) * GK + g0;
  const __bf16* a1p = A  + (size_t)(m0 + r1) * GK + g1;
  const __bf16* b0p = Wm + (size_t)(n0 + r0) * GK + g0;
  const __bf16* b1p = Wm + (size_t)(n0 + r1) * GK + g1;

  const int cp = (qd ^ (lm & 3) ^ ((lm >> 2) & 1)) * 8;

  f32x4 zero = {0.f, 0.f, 0.f, 0.f};
  f32x4 acc[4][4];
  #pragma unroll
  for (int i = 0; i < 4; i++)
    #pragma unroll
    for (int j = 0; j < 4; j++) acc[i][j] = zero;

  for (int k0 = 0; k0 < GK; k0 += 32) {
    gld_lds16(a0p + k0, &As[c0 * 8]);
    gld_lds16(a1p + k0, &As[c1 * 8]);
    gld_lds16(b0p + k0, &Bs[c0 * 8]);
    gld_lds16(b1p + k0, &Bs[c1 * 8]);
    __syncthreads();
    bf16x8 af[4], bfv[4];
    #pragma unroll
    for (int i = 0; i < 4; i++) af[i]  = *(const bf16x8*)&As[(wr * 64 + i * 16 + lm) * 32 + cp];
    #pragma unroll
    for (int j = 0; j < 4; j++) bfv[j] = *(const bf16x8*)&Bs[(wc * 64 + j * 16 + lm) * 32 + cp];
    #pragma unroll
    for (int i = 0; i < 4; i++)
      #pragma unroll
      for (int j = 0; j < 4; j++)
        acc[i][j] = __builtin_amdgcn_mfma_f32_16x16x32_bf16(af[i], bfv[j], acc[i][j], 0, 0, 0);
    __syncthreads();
  }

  if (mode < 2) {
    float* C = (mode == 0) ? C0 : C1;
    #pragma unroll
    for (int i = 0; i < 4; i++) {
      const int row = m0 + wr * 64 + i * 16 + qd * 4;
      #pragma unroll
      for (int j = 0; j < 4; j++) {
        const int col = n0 + wc * 64 + j * 16 + lm;
        #pragma unroll
        for (int r = 0; r < 4; r++)
          C[(size_t)(row + r) * GN + col] = acc[i][j][r];
      }
    }
  } else {
    #pragma unroll
    for (int i = 0; i < 4; i++) {
      const int row = m0 + wr * 64 + i * 16 + qd * 4;    // token
      const int b = row >> 11, s = row & (S_LEN - 1);
      #pragma unroll
      for (int j = 0; j < 4; j++) {
        const int col = n0 + wc * 64 + j * 16 + lm;      // vdim
        const int h = col >> 6, d = col & 63;
        bf16x4 o = { (__bf16)acc[i][j][0], (__bf16)acc[i][j][1],
                     (__bf16)acc[i][j][2], (__bf16)acc[i][j][3] };
        *(bf16x4*)(VtOut + (((size_t)(b * NH + h) * 64 + d) * S_LEN + s)) = o;
      }
    }
  }
}

// ---------------- RMSNorm + RoPE + head split (Q,K only) ----------------
__global__ __launch_bounds__(256) void norm_rope(
    const float* __restrict__ Qf, const float* __restrict__ Kf,
    const float* __restrict__ gain, const int* __restrict__ positions,
    const int* __restrict__ theta_p,
    __bf16* __restrict__ Qh, __bf16* __restrict__ Kh)
{
  const int row = blockIdx.x;             // b*S + s
  const int s = row & (S_LEN - 1), b = row >> 11;
  const int t = threadIdx.x, d0 = t * 4;

  const float4 q = *(const float4*)(Qf + (size_t)row * D_DIM + d0);
  const float4 k = *(const float4*)(Kf + (size_t)row * D_DIM + d0);

  float sq = q.x * q.x + q.y * q.y + q.z * q.z + q.w * q.w;
  float sk = k.x * k.x + k.y * k.y + k.z * k.z + k.w * k.w;
  #pragma unroll
  for (int off = 32; off; off >>= 1) { sq += __shfl_xor(sq, off); sk += __shfl_xor(sk, off); }
  __shared__ float red[8];
  const int lane = t & 63, wv = t >> 6;
  if (lane == 0) { red[wv] = sq; red[4 + wv] = sk; }
  __syncthreads();
  sq = red[0] + red[1] + red[2] + red[3];
  sk = red[4] + red[5] + red[6] + red[7];
  const float invq = rsqrtf(sq * (1.0f / 1024.0f) + 1e-5f);
  const float invk = rsqrtf(sk * (1.0f / 1024.0f) + 1e-5f);

  const float4 g = *(const float4*)(gain + d0);
  const float qn0 = q.x * invq * g.x, qn1 = q.y * invq * g.y;
  const float qn2 = q.z * invq * g.z, qn3 = q.w * invq * g.w;
  const float kn0 = k.x * invk * g.x, kn1 = k.y * invk * g.y;
  const float kn2 = k.z * invk * g.z, kn3 = k.w * invk * g.w;

  const float pos = (float)positions[s];
  const float th  = (float)theta_p[0];
  const int idx = d0 & 63, h = d0 >> 6, p0 = idx >> 1;
  const float lg32 = __log2f(th) * (1.0f / 32.0f);
  const float f0 = fast_exp2(-(float)p0 * lg32);
  const float f1 = fast_exp2(-(float)(p0 + 1) * lg32);
  float s0, cc0, s1, cc1;
  __sincosf(pos * f0, &s0, &cc0);
  __sincosf(pos * f1, &s1, &cc1);

  const float qe0 = qn0 * cc0 - qn1 * s0, qo0 = qn1 * cc0 + qn0 * s0;
  const float qe1 = qn2 * cc1 - qn3 * s1, qo1 = qn3 * cc1 + qn2 * s1;
  const float ke0 = kn0 * cc0 - kn1 * s0, ko0 = kn1 * cc0 + kn0 * s0;
  const float ke1 = kn2 * cc1 - kn3 * s1, ko1 = kn3 * cc1 + kn2 * s1;

  const size_t obase = ((size_t)((b * NH + h) * S_LEN + s)) * 64 + idx;
  bf16x4 qo = { (__bf16)qe0, (__bf16)qo0, (__bf16)qe1, (__bf16)qo1 };
  bf16x4 ko = { (__bf16)ke0, (__bf16)ko0, (__bf16)ke1, (__bf16)ko1 };
  *(bf16x4*)(Qh + obase) = qo;
  *(bf16x4*)(Kh + obase) = ko;
}

// ---------------- causal flash attention, balanced + double-buffered ----------------
// grid (16, 32). Block px handles q-tile px then q-tile 31-px: exactly 33 k-iters.
// Fixed-offset softmax: Q,K are RMSNormed so scores*log2e/8 are bounded (~±16);
// p = exp2(s*SC2 - OFF) is exactly max-free softmax (offset cancels in the
// normalization) — no online max, no rescale, no cross-lane ops in the loop.
__global__ __launch_bounds__(256) void attn_fwd(
    const __bf16* __restrict__ Qh, const __bf16* __restrict__ Kh,
    const __bf16* __restrict__ Vt, __bf16* __restrict__ Ob)
{
  const int bh = blockIdx.y;
  const int px = blockIdx.x;
  const int tid = threadIdx.x, lane = tid & 63, w = tid >> 6;
  const int lm = lane & 15, qd = lane >> 4;

  __shared__ __align__(16) __bf16 smem[2 * 4096 + 2 * 4096 + 4 * 1152];
  __bf16* Ks = smem;                 // [2][4096]
  __bf16* Vs = smem + 8192;          // [2][4096]
  __bf16* Pw = smem + 16384 + w * 1152;

  const int qtA = px, qtB = 31 - px;
  const int rowA = qtA * 64 + w * 16, rowB = qtB * 64 + w * 16;

  const size_t qbase = (size_t)bh * S_LEN * 64;
  const bf16x8 aqA0 = *(const bf16x8*)(Qh + qbase + (size_t)(rowA + lm) * 64 + qd * 8);
  const bf16x8 aqA1 = *(const bf16x8*)(Qh + qbase + (size_t)(rowA + lm) * 64 + 32 + qd * 8);
  const bf16x8 aqB0 = *(const bf16x8*)(Qh + qbase + (size_t)(rowB + lm) * 64 + qd * 8);
  const bf16x8 aqB1 = *(const bf16x8*)(Qh + qbase + (size_t)(rowB + lm) * 64 + 32 + qd * 8);

  const __bf16* Kb = Kh + (size_t)bh * S_LEN * 64;
  const __bf16* Vb = Vt + (size_t)bh * 64 * S_LEN;
  const int c0 = tid, c1 = 256 + tid;
  const int kr0 = c0 >> 3, kr1 = c1 >> 3;
  const int kg0 = ((c0 & 7) ^ (kr0 & 7)) * 8;
  const int kg1 = ((c1 & 7) ^ (kr1 & 7)) * 8;
  const int cpA = (qd ^ (lm & 7)) * 8;
  const int cpB = cpA ^ 32;

  auto stage = [&](int buf, int k0) {
    __bf16* Kd = Ks + buf * 4096;
    __bf16* Vd = Vs + buf * 4096;
    gld_lds16(Kb + (size_t)(k0 + kr0) * 64 + kg0, &Kd[c0 * 8]);
    gld_lds16(Kb + (size_t)(k0 + kr1) * 64 + kg1, &Kd[c1 * 8]);
    gld_lds16(Vb + (size_t)kr0 * S_LEN + k0 + kg0, &Vd[c0 * 8]);
    gld_lds16(Vb + (size_t)kr1 * S_LEN + k0 + kg1, &Vd[c1 * 8]);
  };

  const float SC2 = 0.125f * 1.44269504089f;   // 1/sqrt(64) * log2(e)
  const float OFF = 12.0f;                     // fixed exponent offset (cancels in norm)
  f32x4 zero = {0.f, 0.f, 0.f, 0.f};
  float l[4];
  f32x4 o[4];

  stage(0, 0);

  const int b = bh >> 4, h = bh & 15;

  for (int it = 0; it < 33; ++it) {
    const int seg = (it > qtA);
    const int kt  = seg ? it - qtA - 1 : it;
    const int qt  = seg ? qtB : qtA;
    const int cur = it & 1;

    if (kt == 0) {
      #pragma unroll
      for (int r = 0; r < 4; r++) l[r] = 0.f;
      #pragma unroll
      for (int jb = 0; jb < 4; jb++) o[jb] = zero;
    }

    __syncthreads();                 // buf[cur] staged; buf[cur^1] free
    if (it + 1 < 33) {
      const int nkt = (it + 1 > qtA) ? it - qtA : it + 1;
      stage(cur ^ 1, nkt * 64);
    }

    const __bf16* Kc = Ks + cur * 4096;
    const __bf16* Vc = Vs + cur * 4096;
    const bf16x8 a0 = seg ? aqB0 : aqA0;
    const bf16x8 a1 = seg ? aqB1 : aqA1;
    const int rowg = (seg ? rowB : rowA) + qd * 4;
    const int k0 = kt * 64;

    float p[4][4];
    const bool diag = (kt == qt);
    #pragma unroll
    for (int kb = 0; kb < 4; kb++) {
      const int krow = (kb * 16 + lm) * 64;
      const bf16x8 bk0 = *(const bf16x8*)&Kc[krow + cpA];
      const bf16x8 bk1 = *(const bf16x8*)&Kc[krow + cpB];
      f32x4 sc = zero;
      sc = __builtin_amdgcn_mfma_f32_16x16x32_bf16(a0, bk0, sc, 0, 0, 0);
      sc = __builtin_amdgcn_mfma_f32_16x16x32_bf16(a1, bk1, sc, 0, 0, 0);
      if (diag) {
        const int colg = k0 + kb * 16 + lm;
        #pragma unroll
        for (int r = 0; r < 4; r++) {
          const float e = fast_exp2(fmaf(sc[r], SC2, -OFF));
          p[kb][r] = (colg <= rowg + r) ? e : 0.f;
          l[r] += p[kb][r];
        }
      } else {
        #pragma unroll
        for (int r = 0; r < 4; r++) {
          p[kb][r] = fast_exp2(fmaf(sc[r], SC2, -OFF));
          l[r] += p[kb][r];
        }
      }
    }

    // P: C-layout -> LDS (stride 72) -> A-layout frags
    #pragma unroll
    for (int kb = 0; kb < 4; kb++)
      #pragma unroll
      for (int r = 0; r < 4; r++)
        Pw[(qd * 4 + r) * 72 + kb * 16 + lm] = (__bf16)p[kb][r];

    const bf16x8 ap0 = *(const bf16x8*)&Pw[lm * 72 + qd * 8];
    const bf16x8 ap1 = *(const bf16x8*)&Pw[lm * 72 + 32 + qd * 8];
    #pragma unroll
    for (int jb = 0; jb < 4; jb++) {
      const int vrow = (jb * 16 + lm) * 64;
      const bf16x8 bv0 = *(const bf16x8*)&Vc[vrow + cpA];
      const bf16x8 bv1 = *(const bf16x8*)&Vc[vrow + cpB];
      o[jb] = __builtin_amdgcn_mfma_f32_16x16x32_bf16(ap1, bv1,
              __builtin_amdgcn_mfma_f32_16x16x32_bf16(ap0, bv0, o[jb], 0, 0, 0), 0, 0, 0);
    }

    if (kt == qt) {                  // segment epilogue
      #pragma unroll
      for (int r = 0; r < 4; r++) {
        float lr = l[r];
        #pragma unroll
        for (int off = 8; off; off >>= 1) lr += __shfl_xor(lr, off);
        const float inv = 1.0f / lr;
        const size_t base = ((size_t)(b * S_LEN + rowg + r)) * D_DIM + h * 64;
        #pragma unroll
        for (int jb = 0; jb < 4; jb++)
          Ob[base + jb * 16 + lm] = (__bf16)(o[jb][r] * inv);
      }
    }
  }
}

extern "C" void kernel_launch(void* const* d_in, const int* in_sizes, int n_in,
                              void* d_out, int out_size, void* d_ws, size_t ws_size,
                              hipStream_t stream)
{
  (void)in_sizes; (void)n_in; (void)out_size; (void)ws_size;
  const float* x    = (const float*)d_in[0];
  const float* WQ   = (const float*)d_in[1];
  const float* WK   = (const float*)d_in[2];
  const float* WV   = (const float*)d_in[3];
  const float* WO   = (const float*)d_in[4];
  const float* gain = (const float*)d_in[5];
  const int* positions = (const int*)d_in[6];
  const int* theta     = (const int*)d_in[7];
  float* out = (float*)d_out;

  char* ws = (char*)d_ws;
  const size_t MB = 1024 * 1024;
  __bf16* xb  = (__bf16*)(ws + 0);        //  8 MB
  __bf16* WQb = (__bf16*)(ws + 8  * MB);  //  2 MB
  __bf16* WKb = (__bf16*)(ws + 10 * MB);  //  2 MB
  __bf16* WVb = (__bf16*)(ws + 12 * MB);  //  2 MB
  __bf16* WOb = (__bf16*)(ws + 14 * MB);  //  2 MB
  float*  Qf  = (float*) (ws + 16 * MB);  // 16 MB
  float*  Kf  = (float*) (ws + 32 * MB);  // 16 MB
  __bf16* Vt  = (__bf16*)(ws + 48 * MB);  //  8 MB  [bh][64][s]  (direct from GEMM)
  __bf16* Qh  = (__bf16*)(ws + 56 * MB);  //  8 MB  [bh][s][64]
  __bf16* Kh  = (__bf16*)(ws + 64 * MB);  //  8 MB
  __bf16* Ob  = (__bf16*)(ws + 72 * MB);  //  8 MB  [b][s][1024]

  cast_all<<<8192, 256, 0, stream>>>(x, WQ, WK, WV, WO, xb, WQb, WKb, WVb, WOb);
  gemm_bt<<<dim3(8, 32, 3), 256, 0, stream>>>(xb, WQb, WKb, WVb, Qf, Kf, Vt);
  norm_rope<<<4096, 256, 0, stream>>>(Qf, Kf, gain, positions, theta, Qh, Kh);
  attn_fwd<<<dim3(16, 32), 256, 0, stream>>>(Qh, Kh, Vt, Ob);
  gemm_bt<<<dim3(8, 32, 1), 256, 0, stream>>>(Ob, WOb, WOb, WOb, out, out, (__bf16*)out);
}

// Round 4
// 220.410 us; speedup vs baseline: 1.5474x; 1.0358x over previous
//
#include <hip/hip_runtime.h>
#include <hip/hip_bf16.h>

typedef __attribute__((ext_vector_type(8))) __bf16 bf16x8;
typedef __attribute__((ext_vector_type(4))) __bf16 bf16x4;
typedef __attribute__((ext_vector_type(4))) float  f32x4;

#define S_LEN 2048
#define D_DIM 1024
#define NH    16
#define GK    1024
#define GN    1024

__device__ __forceinline__ float fast_exp2(float x) {
#if __has_builtin(__builtin_amdgcn_exp2f)
  return __builtin_amdgcn_exp2f(x);
#else
  return exp2f(x);
#endif
}

// async global->LDS, 16B per lane; HW scatters to wave-uniform-base + lane*16
__device__ __forceinline__ void gld_lds16(const void* g, void* l) {
  __builtin_amdgcn_global_load_lds(
      (const __attribute__((address_space(1))) unsigned int*)g,
      (__attribute__((address_space(3))) unsigned int*)l, 16, 0, 0);
}

// ---------------- fused fp32 -> bf16 cast, grid-stride ----------------
__global__ __launch_bounds__(256) void cast_all(
    const float* __restrict__ x,  const float* __restrict__ wq, const float* __restrict__ wk,
    const float* __restrict__ wv, const float* __restrict__ wo,
    __bf16* __restrict__ xb, __bf16* __restrict__ wqb, __bf16* __restrict__ wkb,
    __bf16* __restrict__ wvb, __bf16* __restrict__ wob)
{
  const int NTOT = 2 << 20;                      // 2M float4 chunks
  for (int i = blockIdx.x * 256 + threadIdx.x; i < NTOT; i += 1024 * 256) {
    const float* s; __bf16* d; int off;
    if (i < (1 << 20)) { s = x; d = xb; off = i; }
    else {
      const int j = i - (1 << 20);
      const int r = j >> 18; off = j & ((1 << 18) - 1);
      s = (r == 0) ? wq : (r == 1) ? wk : (r == 2) ? wv : wo;
      d = (r == 0) ? wqb : (r == 1) ? wkb : (r == 2) ? wvb : wob;
    }
    float4 v = ((const float4*)s)[off];
    bf16x4 o = { (__bf16)v.x, (__bf16)v.y, (__bf16)v.z, (__bf16)v.w };
    ((bf16x4*)d)[off] = o;
  }
}

// ---------------- GEMM 128x128: C[m][n] = sum_k A[m][k]*W[n][k] ----------------
// z=0/1: fp32 C row-major (Q/K). z=2: bf16 direct to Vt [bh][d][s].
__global__ __launch_bounds__(256) void gemm_bt(
    const __bf16* __restrict__ A,
    const __bf16* __restrict__ W0, const __bf16* __restrict__ W1, const __bf16* __restrict__ W2,
    float* __restrict__ C0, float* __restrict__ C1, __bf16* __restrict__ VtOut)
{
  const int mode = blockIdx.z;
  const __bf16* Wm = (mode == 0) ? W0 : (mode == 1) ? W1 : W2;

  __shared__ __align__(16) __bf16 As[128 * 32];
  __shared__ __align__(16) __bf16 Bs[128 * 32];

  const int tid  = threadIdx.x;
  const int lane = tid & 63;
  const int w    = tid >> 6;
  const int wr   = w >> 1, wc = w & 1;
  const int lm   = lane & 15, qd = lane >> 4;
  const int m0 = blockIdx.y * 128, n0 = blockIdx.x * 128;

  const int c0 = tid, c1 = 256 + tid;
  const int r0 = c0 >> 2, r1 = c1 >> 2;
  const int g0 = ((c0 & 3) ^ (r0 & 3) ^ ((r0 >> 2) & 1)) * 8;
  const int g1 = ((c1 & 3) ^ (r1 & 3) ^ ((r1 >> 2) & 1)) * 8;
  const __bf16* a0p = A  + (size_t)(m0 + r0) * GK + g0;
  const __bf16* a1p = A  + (size_t)(m0 + r1) * GK + g1;
  const __bf16* b0p = Wm + (size_t)(n0 + r0) * GK + g0;
  const __bf16* b1p = Wm + (size_t)(n0 + r1) * GK + g1;

  const int cp = (qd ^ (lm & 3) ^ ((lm >> 2) & 1)) * 8;

  f32x4 zero = {0.f, 0.f, 0.f, 0.f};
  f32x4 acc[4][4];
  #pragma unroll
  for (int i = 0; i < 4; i++)
    #pragma unroll
    for (int j = 0; j < 4; j++) acc[i][j] = zero;

  for (int k0 = 0; k0 < GK; k0 += 32) {
    gld_lds16(a0p + k0, &As[c0 * 8]);
    gld_lds16(a1p + k0, &As[c1 * 8]);
    gld_lds16(b0p + k0, &Bs[c0 * 8]);
    gld_lds16(b1p + k0, &Bs[c1 * 8]);
    __syncthreads();
    bf16x8 af[4], bfv[4];
    #pragma unroll
    for (int i = 0; i < 4; i++) af[i]  = *(const bf16x8*)&As[(wr * 64 + i * 16 + lm) * 32 + cp];
    #pragma unroll
    for (int j = 0; j < 4; j++) bfv[j] = *(const bf16x8*)&Bs[(wc * 64 + j * 16 + lm) * 32 + cp];
    #pragma unroll
    for (int i = 0; i < 4; i++)
      #pragma unroll
      for (int j = 0; j < 4; j++)
        acc[i][j] = __builtin_amdgcn_mfma_f32_16x16x32_bf16(af[i], bfv[j], acc[i][j], 0, 0, 0);
    __syncthreads();
  }

  if (mode < 2) {
    float* C = (mode == 0) ? C0 : C1;
    #pragma unroll
    for (int i = 0; i < 4; i++) {
      const int row = m0 + wr * 64 + i * 16 + qd * 4;
      #pragma unroll
      for (int j = 0; j < 4; j++) {
        const int col = n0 + wc * 64 + j * 16 + lm;
        #pragma unroll
        for (int r = 0; r < 4; r++)
          C[(size_t)(row + r) * GN + col] = acc[i][j][r];
      }
    }
  } else {
    #pragma unroll
    for (int i = 0; i < 4; i++) {
      const int row = m0 + wr * 64 + i * 16 + qd * 4;    // token
      const int b = row >> 11, s = row & (S_LEN - 1);
      #pragma unroll
      for (int j = 0; j < 4; j++) {
        const int col = n0 + wc * 64 + j * 16 + lm;      // vdim
        const int h = col >> 6, d = col & 63;
        bf16x4 o = { (__bf16)acc[i][j][0], (__bf16)acc[i][j][1],
                     (__bf16)acc[i][j][2], (__bf16)acc[i][j][3] };
        *(bf16x4*)(VtOut + (((size_t)(b * NH + h) * 64 + d) * S_LEN + s)) = o;
      }
    }
  }
}

// ---------------- GEMM 64x128 (fp32 out): for the N=1024 out-projection ----------------
// grid (8, 64) = 512 blocks = 2 blocks/CU (vs 1 for 128x128). Waves 2x2, each 32x64.
__global__ __launch_bounds__(256) void gemm_out64(
    const __bf16* __restrict__ A, const __bf16* __restrict__ Wm, float* __restrict__ C)
{
  __shared__ __align__(16) __bf16 As[64 * 32];    // 4 KB
  __shared__ __align__(16) __bf16 Bs[128 * 32];   // 8 KB

  const int tid  = threadIdx.x;
  const int lane = tid & 63;
  const int w    = tid >> 6;
  const int wr   = w >> 1, wc = w & 1;
  const int lm   = lane & 15, qd = lane >> 4;
  const int m0 = blockIdx.y * 64, n0 = blockIdx.x * 128;

  // A: 256 chunks (1/thread); B: 512 chunks (2/thread)
  const int ca = tid;              const int ra = ca >> 2;
  const int cb0 = tid, cb1 = 256 + tid;
  const int rb0 = cb0 >> 2, rb1 = cb1 >> 2;
  const int ga  = ((ca  & 3) ^ (ra  & 3) ^ ((ra  >> 2) & 1)) * 8;
  const int gb0 = ((cb0 & 3) ^ (rb0 & 3) ^ ((rb0 >> 2) & 1)) * 8;
  const int gb1 = ((cb1 & 3) ^ (rb1 & 3) ^ ((rb1 >> 2) & 1)) * 8;
  const __bf16* ap  = A  + (size_t)(m0 + ra)  * GK + ga;
  const __bf16* bp0 = Wm + (size_t)(n0 + rb0) * GK + gb0;
  const __bf16* bp1 = Wm + (size_t)(n0 + rb1) * GK + gb1;

  const int cp = (qd ^ (lm & 3) ^ ((lm >> 2) & 1)) * 8;

  f32x4 zero = {0.f, 0.f, 0.f, 0.f};
  f32x4 acc[2][4];
  #pragma unroll
  for (int i = 0; i < 2; i++)
    #pragma unroll
    for (int j = 0; j < 4; j++) acc[i][j] = zero;

  for (int k0 = 0; k0 < GK; k0 += 32) {
    gld_lds16(ap  + k0, &As[ca  * 8]);
    gld_lds16(bp0 + k0, &Bs[cb0 * 8]);
    gld_lds16(bp1 + k0, &Bs[cb1 * 8]);
    __syncthreads();
    bf16x8 af[2], bfv[4];
    #pragma unroll
    for (int i = 0; i < 2; i++) af[i]  = *(const bf16x8*)&As[(wr * 32 + i * 16 + lm) * 32 + cp];
    #pragma unroll
    for (int j = 0; j < 4; j++) bfv[j] = *(const bf16x8*)&Bs[(wc * 64 + j * 16 + lm) * 32 + cp];
    #pragma unroll
    for (int i = 0; i < 2; i++)
      #pragma unroll
      for (int j = 0; j < 4; j++)
        acc[i][j] = __builtin_amdgcn_mfma_f32_16x16x32_bf16(af[i], bfv[j], acc[i][j], 0, 0, 0);
    __syncthreads();
  }

  #pragma unroll
  for (int i = 0; i < 2; i++) {
    const int row = m0 + wr * 32 + i * 16 + qd * 4;
    #pragma unroll
    for (int j = 0; j < 4; j++) {
      const int col = n0 + wc * 64 + j * 16 + lm;
      #pragma unroll
      for (int r = 0; r < 4; r++)
        C[(size_t)(row + r) * GN + col] = acc[i][j][r];
    }
  }
}

// ---------------- RMSNorm + RoPE + head split (Q,K only) ----------------
__global__ __launch_bounds__(256) void norm_rope(
    const float* __restrict__ Qf, const float* __restrict__ Kf,
    const float* __restrict__ gain, const int* __restrict__ positions,
    const int* __restrict__ theta_p,
    __bf16* __restrict__ Qh, __bf16* __restrict__ Kh)
{
  const int row = blockIdx.x;             // b*S + s
  const int s = row & (S_LEN - 1), b = row >> 11;
  const int t = threadIdx.x, d0 = t * 4;

  const float4 q = *(const float4*)(Qf + (size_t)row * D_DIM + d0);
  const float4 k = *(const float4*)(Kf + (size_t)row * D_DIM + d0);

  float sq = q.x * q.x + q.y * q.y + q.z * q.z + q.w * q.w;
  float sk = k.x * k.x + k.y * k.y + k.z * k.z + k.w * k.w;
  #pragma unroll
  for (int off = 32; off; off >>= 1) { sq += __shfl_xor(sq, off); sk += __shfl_xor(sk, off); }
  __shared__ float red[8];
  const int lane = t & 63, wv = t >> 6;
  if (lane == 0) { red[wv] = sq; red[4 + wv] = sk; }
  __syncthreads();
  sq = red[0] + red[1] + red[2] + red[3];
  sk = red[4] + red[5] + red[6] + red[7];
  const float invq = rsqrtf(sq * (1.0f / 1024.0f) + 1e-5f);
  const float invk = rsqrtf(sk * (1.0f / 1024.0f) + 1e-5f);

  const float4 g = *(const float4*)(gain + d0);
  const float qn0 = q.x * invq * g.x, qn1 = q.y * invq * g.y;
  const float qn2 = q.z * invq * g.z, qn3 = q.w * invq * g.w;
  const float kn0 = k.x * invk * g.x, kn1 = k.y * invk * g.y;
  const float kn2 = k.z * invk * g.z, kn3 = k.w * invk * g.w;

  const float pos = (float)positions[s];
  const float th  = (float)theta_p[0];
  const int idx = d0 & 63, h = d0 >> 6, p0 = idx >> 1;
  const float lg32 = __log2f(th) * (1.0f / 32.0f);
  const float f0 = fast_exp2(-(float)p0 * lg32);
  const float f1 = fast_exp2(-(float)(p0 + 1) * lg32);
  float s0, cc0, s1, cc1;
  __sincosf(pos * f0, &s0, &cc0);
  __sincosf(pos * f1, &s1, &cc1);

  const float qe0 = qn0 * cc0 - qn1 * s0, qo0 = qn1 * cc0 + qn0 * s0;
  const float qe1 = qn2 * cc1 - qn3 * s1, qo1 = qn3 * cc1 + qn2 * s1;
  const float ke0 = kn0 * cc0 - kn1 * s0, ko0 = kn1 * cc0 + kn0 * s0;
  const float ke1 = kn2 * cc1 - kn3 * s1, ko1 = kn3 * cc1 + kn2 * s1;

  const size_t obase = ((size_t)((b * NH + h) * S_LEN + s)) * 64 + idx;
  bf16x4 qo = { (__bf16)qe0, (__bf16)qo0, (__bf16)qe1, (__bf16)qo1 };
  bf16x4 ko = { (__bf16)ke0, (__bf16)ko0, (__bf16)ke1, (__bf16)ko1 };
  *(bf16x4*)(Qh + obase) = qo;
  *(bf16x4*)(Kh + obase) = ko;
}

// ---------------- causal flash attention, balanced + double-buffered + XCD-local ----
// 512 blocks; bid mapped so all 16 q-tile-pair blocks of one bh share an XCD
// (bid%8 heuristic): K/V (512 KB/bh, 4 bh/XCD = 2 MB) stays L2-resident.
__global__ __launch_bounds__(256) void attn_fwd(
    const __bf16* __restrict__ Qh, const __bf16* __restrict__ Kh,
    const __bf16* __restrict__ Vt, __bf16* __restrict__ Ob)
{
  const int bid = blockIdx.x + 16 * blockIdx.y;
  const int px  = bid >> 5;
  const int rr  = bid & 31;
  const int bh  = (rr & 7) * 4 + (rr >> 3);      // same-bh blocks -> same bid%8
  const int tid = threadIdx.x, lane = tid & 63, w = tid >> 6;
  const int lm = lane & 15, qd = lane >> 4;

  __shared__ __align__(16) __bf16 smem[2 * 4096 + 2 * 4096 + 4 * 1152];
  __bf16* Ks = smem;                 // [2][4096]
  __bf16* Vs = smem + 8192;          // [2][4096]
  __bf16* Pw = smem + 16384 + w * 1152;

  const int qtA = px, qtB = 31 - px;
  const int rowA = qtA * 64 + w * 16, rowB = qtB * 64 + w * 16;

  const size_t qbase = (size_t)bh * S_LEN * 64;
  const bf16x8 aqA0 = *(const bf16x8*)(Qh + qbase + (size_t)(rowA + lm) * 64 + qd * 8);
  const bf16x8 aqA1 = *(const bf16x8*)(Qh + qbase + (size_t)(rowA + lm) * 64 + 32 + qd * 8);
  const bf16x8 aqB0 = *(const bf16x8*)(Qh + qbase + (size_t)(rowB + lm) * 64 + qd * 8);
  const bf16x8 aqB1 = *(const bf16x8*)(Qh + qbase + (size_t)(rowB + lm) * 64 + 32 + qd * 8);

  const __bf16* Kb = Kh + (size_t)bh * S_LEN * 64;
  const __bf16* Vb = Vt + (size_t)bh * 64 * S_LEN;
  const int c0 = tid, c1 = 256 + tid;
  const int kr0 = c0 >> 3, kr1 = c1 >> 3;
  const int kg0 = ((c0 & 7) ^ (kr0 & 7)) * 8;
  const int kg1 = ((c1 & 7) ^ (kr1 & 7)) * 8;
  const int cpA = (qd ^ (lm & 7)) * 8;
  const int cpB = cpA ^ 32;

  auto stage = [&](int buf, int k0) {
    __bf16* Kd = Ks + buf * 4096;
    __bf16* Vd = Vs + buf * 4096;
    gld_lds16(Kb + (size_t)(k0 + kr0) * 64 + kg0, &Kd[c0 * 8]);
    gld_lds16(Kb + (size_t)(k0 + kr1) * 64 + kg1, &Kd[c1 * 8]);
    gld_lds16(Vb + (size_t)kr0 * S_LEN + k0 + kg0, &Vd[c0 * 8]);
    gld_lds16(Vb + (size_t)kr1 * S_LEN + k0 + kg1, &Vd[c1 * 8]);
  };

  const float SC2 = 0.125f * 1.44269504089f;   // 1/sqrt(64) * log2(e)
  const float OFF = 12.0f;                     // fixed exponent offset (cancels in norm)
  f32x4 zero = {0.f, 0.f, 0.f, 0.f};
  float l[4];
  f32x4 o[4];

  stage(0, 0);

  const int b = bh >> 4, h = bh & 15;

  for (int it = 0; it < 33; ++it) {
    const int seg = (it > qtA);
    const int kt  = seg ? it - qtA - 1 : it;
    const int qt  = seg ? qtB : qtA;
    const int cur = it & 1;

    if (kt == 0) {
      #pragma unroll
      for (int r = 0; r < 4; r++) l[r] = 0.f;
      #pragma unroll
      for (int jb = 0; jb < 4; jb++) o[jb] = zero;
    }

    __syncthreads();                 // buf[cur] staged; buf[cur^1] free
    if (it + 1 < 33) {
      const int nkt = (it + 1 > qtA) ? it - qtA : it + 1;
      stage(cur ^ 1, nkt * 64);
    }

    const __bf16* Kc = Ks + cur * 4096;
    const __bf16* Vc = Vs + cur * 4096;
    const bf16x8 a0 = seg ? aqB0 : aqA0;
    const bf16x8 a1 = seg ? aqB1 : aqA1;
    const int rowg = (seg ? rowB : rowA) + qd * 4;
    const int k0 = kt * 64;

    float p[4][4];
    const bool diag = (kt == qt);
    #pragma unroll
    for (int kb = 0; kb < 4; kb++) {
      const int krow = (kb * 16 + lm) * 64;
      const bf16x8 bk0 = *(const bf16x8*)&Kc[krow + cpA];
      const bf16x8 bk1 = *(const bf16x8*)&Kc[krow + cpB];
      f32x4 sc = zero;
      sc = __builtin_amdgcn_mfma_f32_16x16x32_bf16(a0, bk0, sc, 0, 0, 0);
      sc = __builtin_amdgcn_mfma_f32_16x16x32_bf16(a1, bk1, sc, 0, 0, 0);
      if (diag) {
        const int colg = k0 + kb * 16 + lm;
        #pragma unroll
        for (int r = 0; r < 4; r++) {
          const float e = fast_exp2(fmaf(sc[r], SC2, -OFF));
          p[kb][r] = (colg <= rowg + r) ? e : 0.f;
          l[r] += p[kb][r];
        }
      } else {
        #pragma unroll
        for (int r = 0; r < 4; r++) {
          p[kb][r] = fast_exp2(fmaf(sc[r], SC2, -OFF));
          l[r] += p[kb][r];
        }
      }
    }

    // P: C-layout -> LDS (stride 72) -> A-layout frags
    #pragma unroll
    for (int kb = 0; kb < 4; kb++)
      #pragma unroll
      for (int r = 0; r < 4; r++)
        Pw[(qd * 4 + r) * 72 + kb * 16 + lm] = (__bf16)p[kb][r];

    const bf16x8 ap0 = *(const bf16x8*)&Pw[lm * 72 + qd * 8];
    const bf16x8 ap1 = *(const bf16x8*)&Pw[lm * 72 + 32 + qd * 8];
    #pragma unroll
    for (int jb = 0; jb < 4; jb++) {
      const int vrow = (jb * 16 + lm) * 64;
      const bf16x8 bv0 = *(const bf16x8*)&Vc[vrow + cpA];
      const bf16x8 bv1 = *(const bf16x8*)&Vc[vrow + cpB];
      o[jb] = __builtin_amdgcn_mfma_f32_16x16x32_bf16(ap1, bv1,
              __builtin_amdgcn_mfma_f32_16x16x32_bf16(ap0, bv0, o[jb], 0, 0, 0), 0, 0, 0);
    }

    if (kt == qt) {                  // segment epilogue
      #pragma unroll
      for (int r = 0; r < 4; r++) {
        float lr = l[r];
        #pragma unroll
        for (int off = 8; off; off >>= 1) lr += __shfl_xor(lr, off);
        const float inv = 1.0f / lr;
        const size_t base = ((size_t)(b * S_LEN + rowg + r)) * D_DIM + h * 64;
        #pragma unroll
        for (int jb = 0; jb < 4; jb++)
          Ob[base + jb * 16 + lm] = (__bf16)(o[jb][r] * inv);
      }
    }
  }
}

extern "C" void kernel_launch(void* const* d_in, const int* in_sizes, int n_in,
                              void* d_out, int out_size, void* d_ws, size_t ws_size,
                              hipStream_t stream)
{
  (void)in_sizes; (void)n_in; (void)out_size; (void)ws_size;
  const float* x    = (const float*)d_in[0];
  const float* WQ   = (const float*)d_in[1];
  const float* WK   = (const float*)d_in[2];
  const float* WV   = (const float*)d_in[3];
  const float* WO   = (const float*)d_in[4];
  const float* gain = (const float*)d_in[5];
  const int* positions = (const int*)d_in[6];
  const int* theta     = (const int*)d_in[7];
  float* out = (float*)d_out;

  char* ws = (char*)d_ws;
  const size_t MB = 1024 * 1024;
  __bf16* xb  = (__bf16*)(ws + 0);        //  8 MB
  __bf16* WQb = (__bf16*)(ws + 8  * MB);  //  2 MB
  __bf16* WKb = (__bf16*)(ws + 10 * MB);  //  2 MB
  __bf16* WVb = (__bf16*)(ws + 12 * MB);  //  2 MB
  __bf16* WOb = (__bf16*)(ws + 14 * MB);  //  2 MB
  float*  Qf  = (float*) (ws + 16 * MB);  // 16 MB
  float*  Kf  = (float*) (ws + 32 * MB);  // 16 MB
  __bf16* Vt  = (__bf16*)(ws + 48 * MB);  //  8 MB  [bh][64][s]  (direct from GEMM)
  __bf16* Qh  = (__bf16*)(ws + 56 * MB);  //  8 MB  [bh][s][64]
  __bf16* Kh  = (__bf16*)(ws + 64 * MB);  //  8 MB
  __bf16* Ob  = (__bf16*)(ws + 72 * MB);  //  8 MB  [b][s][1024]

  cast_all<<<1024, 256, 0, stream>>>(x, WQ, WK, WV, WO, xb, WQb, WKb, WVb, WOb);
  gemm_bt<<<dim3(8, 32, 3), 256, 0, stream>>>(xb, WQb, WKb, WVb, Qf, Kf, Vt);
  norm_rope<<<4096, 256, 0, stream>>>(Qf, Kf, gain, positions, theta, Qh, Kh);
  attn_fwd<<<dim3(16, 32), 256, 0, stream>>>(Qh, Kh, Vt, Ob);
  gemm_out64<<<dim3(8, 64), 256, 0, stream>>>(Ob, WOb, out);
}

// Round 5
// 203.111 us; speedup vs baseline: 1.6792x; 1.0852x over previous
//
#include <hip/hip_runtime.h>
#include <hip/hip_bf16.h>

typedef __attribute__((ext_vector_type(8))) __bf16 bf16x8;
typedef __attribute__((ext_vector_type(4))) __bf16 bf16x4;
typedef __attribute__((ext_vector_type(4))) float  f32x4;

#define S_LEN 2048
#define D_DIM 1024
#define NH    16
#define GK    1024
#define GN    1024

__device__ __forceinline__ float fast_exp2(float x) {
#if __has_builtin(__builtin_amdgcn_exp2f)
  return __builtin_amdgcn_exp2f(x);
#else
  return exp2f(x);
#endif
}

// async global->LDS, 16B per lane; HW scatters to wave-uniform-base + lane*16
__device__ __forceinline__ void gld_lds16(const void* g, void* l) {
  __builtin_amdgcn_global_load_lds(
      (const __attribute__((address_space(1))) unsigned int*)g,
      (__attribute__((address_space(3))) unsigned int*)l, 16, 0, 0);
}

// ---------------- fused fp32 -> bf16 cast, grid-stride ----------------
__global__ __launch_bounds__(256) void cast_all(
    const float* __restrict__ x,  const float* __restrict__ wq, const float* __restrict__ wk,
    const float* __restrict__ wv, const float* __restrict__ wo,
    __bf16* __restrict__ xb, __bf16* __restrict__ wqb, __bf16* __restrict__ wkb,
    __bf16* __restrict__ wvb, __bf16* __restrict__ wob)
{
  const int NTOT = 2 << 20;                      // 2M float4 chunks
  for (int i = blockIdx.x * 256 + threadIdx.x; i < NTOT; i += 1024 * 256) {
    const float* s; __bf16* d; int off;
    if (i < (1 << 20)) { s = x; d = xb; off = i; }
    else {
      const int j = i - (1 << 20);
      const int r = j >> 18; off = j & ((1 << 18) - 1);
      s = (r == 0) ? wq : (r == 1) ? wk : (r == 2) ? wv : wo;
      d = (r == 0) ? wqb : (r == 1) ? wkb : (r == 2) ? wvb : wob;
    }
    float4 v = ((const float4*)s)[off];
    bf16x4 o = { (__bf16)v.x, (__bf16)v.y, (__bf16)v.z, (__bf16)v.w };
    ((bf16x4*)d)[off] = o;
  }
}

// ---------------- GEMM 128x128, BK=64: C[m][n] = sum_k A[m][k]*W[n][k] ----------------
// 16 k-iterations (half the barrier drains of BK=32). Rows of 64 elems = 8 chunks,
// XOR swizzle cpos = chunk ^ (row&7) -> frag ds_read_b128 is 2-way-bank (free).
// z=0/1: bf16 C row-major (Q/K pre-norm). z=2: bf16 direct to Vt [bh][d][s].
__global__ __launch_bounds__(256) void gemm_bt(
    const __bf16* __restrict__ A,
    const __bf16* __restrict__ W0, const __bf16* __restrict__ W1, const __bf16* __restrict__ W2,
    __bf16* __restrict__ C0, __bf16* __restrict__ C1, __bf16* __restrict__ VtOut)
{
  const int mode = blockIdx.z;
  const __bf16* Wm = (mode == 0) ? W0 : (mode == 1) ? W1 : W2;

  __shared__ __align__(16) __bf16 As[128 * 64];   // 16 KB
  __shared__ __align__(16) __bf16 Bs[128 * 64];   // 16 KB

  const int tid  = threadIdx.x;
  const int lane = tid & 63;
  const int w    = tid >> 6;
  const int wr   = w >> 1, wc = w & 1;
  const int lm   = lane & 15, qd = lane >> 4;
  const int m0 = blockIdx.y * 128, n0 = blockIdx.x * 128;

  // staging: 1024 chunks/tile, 4/thread; row = c>>3, LDS cpos = c&7 holds global
  // chunk (c&7)^(row&7)
  const __bf16* ap[4]; const __bf16* bp[4]; int lo[4];
  #pragma unroll
  for (int j = 0; j < 4; j++) {
    const int c = tid + 256 * j;
    const int r = c >> 3, cpos = c & 7;
    const int g = (cpos ^ (r & 7)) * 8;
    ap[j] = A  + (size_t)(m0 + r) * GK + g;
    bp[j] = Wm + (size_t)(n0 + r) * GK + g;
    lo[j] = c * 8;
  }

  const int sw = lm & 7;            // frag row swizzle (rows are base16 + lm)

  f32x4 zero = {0.f, 0.f, 0.f, 0.f};
  f32x4 acc[4][4];
  #pragma unroll
  for (int i = 0; i < 4; i++)
    #pragma unroll
    for (int j = 0; j < 4; j++) acc[i][j] = zero;

  for (int k0 = 0; k0 < GK; k0 += 64) {
    #pragma unroll
    for (int j = 0; j < 4; j++) {
      gld_lds16(ap[j] + k0, &As[lo[j]]);
      gld_lds16(bp[j] + k0, &Bs[lo[j]]);
    }
    __syncthreads();
    #pragma unroll
    for (int half = 0; half < 2; half++) {
      const int cph = ((qd + 4 * half) ^ sw) * 8;
      bf16x8 af[4], bfv[4];
      #pragma unroll
      for (int i = 0; i < 4; i++) af[i]  = *(const bf16x8*)&As[(wr * 64 + i * 16 + lm) * 64 + cph];
      #pragma unroll
      for (int j = 0; j < 4; j++) bfv[j] = *(const bf16x8*)&Bs[(wc * 64 + j * 16 + lm) * 64 + cph];
      #pragma unroll
      for (int i = 0; i < 4; i++)
        #pragma unroll
        for (int j = 0; j < 4; j++)
          acc[i][j] = __builtin_amdgcn_mfma_f32_16x16x32_bf16(af[i], bfv[j], acc[i][j], 0, 0, 0);
    }
    __syncthreads();
  }

  if (mode < 2) {
    __bf16* C = (mode == 0) ? C0 : C1;
    #pragma unroll
    for (int i = 0; i < 4; i++) {
      const int row = m0 + wr * 64 + i * 16 + qd * 4;
      #pragma unroll
      for (int j = 0; j < 4; j++) {
        const int col = n0 + wc * 64 + j * 16 + lm;
        #pragma unroll
        for (int r = 0; r < 4; r++)
          C[(size_t)(row + r) * GN + col] = (__bf16)acc[i][j][r];
      }
    }
  } else {
    #pragma unroll
    for (int i = 0; i < 4; i++) {
      const int row = m0 + wr * 64 + i * 16 + qd * 4;    // token
      const int b = row >> 11, s = row & (S_LEN - 1);
      #pragma unroll
      for (int j = 0; j < 4; j++) {
        const int col = n0 + wc * 64 + j * 16 + lm;      // vdim
        const int h = col >> 6, d = col & 63;
        bf16x4 o = { (__bf16)acc[i][j][0], (__bf16)acc[i][j][1],
                     (__bf16)acc[i][j][2], (__bf16)acc[i][j][3] };
        *(bf16x4*)(VtOut + (((size_t)(b * NH + h) * 64 + d) * S_LEN + s)) = o;
      }
    }
  }
}

// ---------------- GEMM 64x128, BK=64 (fp32 out): out-projection ----------------
// grid (8, 64) = 512 blocks = 2 blocks/CU. Waves 2x2, each 32x64.
__global__ __launch_bounds__(256) void gemm_out64(
    const __bf16* __restrict__ A, const __bf16* __restrict__ Wm, float* __restrict__ C)
{
  __shared__ __align__(16) __bf16 As[64 * 64];    //  8 KB
  __shared__ __align__(16) __bf16 Bs[128 * 64];   // 16 KB

  const int tid  = threadIdx.x;
  const int lane = tid & 63;
  const int w    = tid >> 6;
  const int wr   = w >> 1, wc = w & 1;
  const int lm   = lane & 15, qd = lane >> 4;
  const int m0 = blockIdx.y * 64, n0 = blockIdx.x * 128;

  // A: 512 chunks (2/thread); B: 1024 chunks (4/thread)
  const __bf16* ap[2]; int loA[2];
  #pragma unroll
  for (int j = 0; j < 2; j++) {
    const int c = tid + 256 * j;
    const int r = c >> 3, cpos = c & 7;
    ap[j] = A + (size_t)(m0 + r) * GK + (cpos ^ (r & 7)) * 8;
    loA[j] = c * 8;
  }
  const __bf16* bp[4]; int loB[4];
  #pragma unroll
  for (int j = 0; j < 4; j++) {
    const int c = tid + 256 * j;
    const int r = c >> 3, cpos = c & 7;
    bp[j] = Wm + (size_t)(n0 + r) * GK + (cpos ^ (r & 7)) * 8;
    loB[j] = c * 8;
  }

  const int sw = lm & 7;

  f32x4 zero = {0.f, 0.f, 0.f, 0.f};
  f32x4 acc[2][4];
  #pragma unroll
  for (int i = 0; i < 2; i++)
    #pragma unroll
    for (int j = 0; j < 4; j++) acc[i][j] = zero;

  for (int k0 = 0; k0 < GK; k0 += 64) {
    #pragma unroll
    for (int j = 0; j < 2; j++) gld_lds16(ap[j] + k0, &As[loA[j]]);
    #pragma unroll
    for (int j = 0; j < 4; j++) gld_lds16(bp[j] + k0, &Bs[loB[j]]);
    __syncthreads();
    #pragma unroll
    for (int half = 0; half < 2; half++) {
      const int cph = ((qd + 4 * half) ^ sw) * 8;
      bf16x8 af[2], bfv[4];
      #pragma unroll
      for (int i = 0; i < 2; i++) af[i]  = *(const bf16x8*)&As[(wr * 32 + i * 16 + lm) * 64 + cph];
      #pragma unroll
      for (int j = 0; j < 4; j++) bfv[j] = *(const bf16x8*)&Bs[(wc * 64 + j * 16 + lm) * 64 + cph];
      #pragma unroll
      for (int i = 0; i < 2; i++)
        #pragma unroll
        for (int j = 0; j < 4; j++)
          acc[i][j] = __builtin_amdgcn_mfma_f32_16x16x32_bf16(af[i], bfv[j], acc[i][j], 0, 0, 0);
    }
    __syncthreads();
  }

  #pragma unroll
  for (int i = 0; i < 2; i++) {
    const int row = m0 + wr * 32 + i * 16 + qd * 4;
    #pragma unroll
    for (int j = 0; j < 4; j++) {
      const int col = n0 + wc * 64 + j * 16 + lm;
      #pragma unroll
      for (int r = 0; r < 4; r++)
        C[(size_t)(row + r) * GN + col] = acc[i][j][r];
    }
  }
}

// ---------------- RMSNorm + RoPE + head split (Q,K only; bf16 in) ----------------
__global__ __launch_bounds__(256) void norm_rope(
    const __bf16* __restrict__ Qf, const __bf16* __restrict__ Kf,
    const float* __restrict__ gain, const int* __restrict__ positions,
    const int* __restrict__ theta_p,
    __bf16* __restrict__ Qh, __bf16* __restrict__ Kh)
{
  const int row = blockIdx.x;             // b*S + s
  const int s = row & (S_LEN - 1), b = row >> 11;
  const int t = threadIdx.x, d0 = t * 4;

  const bf16x4 qv = *(const bf16x4*)(Qf + (size_t)row * D_DIM + d0);
  const bf16x4 kv = *(const bf16x4*)(Kf + (size_t)row * D_DIM + d0);
  const float q0 = (float)qv[0], q1 = (float)qv[1], q2 = (float)qv[2], q3 = (float)qv[3];
  const float k0 = (float)kv[0], k1 = (float)kv[1], k2 = (float)kv[2], k3 = (float)kv[3];

  float sq = q0 * q0 + q1 * q1 + q2 * q2 + q3 * q3;
  float sk = k0 * k0 + k1 * k1 + k2 * k2 + k3 * k3;
  #pragma unroll
  for (int off = 32; off; off >>= 1) { sq += __shfl_xor(sq, off); sk += __shfl_xor(sk, off); }
  __shared__ float red[8];
  const int lane = t & 63, wv = t >> 6;
  if (lane == 0) { red[wv] = sq; red[4 + wv] = sk; }
  __syncthreads();
  sq = red[0] + red[1] + red[2] + red[3];
  sk = red[4] + red[5] + red[6] + red[7];
  const float invq = rsqrtf(sq * (1.0f / 1024.0f) + 1e-5f);
  const float invk = rsqrtf(sk * (1.0f / 1024.0f) + 1e-5f);

  const float4 g = *(const float4*)(gain + d0);
  const float qn0 = q0 * invq * g.x, qn1 = q1 * invq * g.y;
  const float qn2 = q2 * invq * g.z, qn3 = q3 * invq * g.w;
  const float kn0 = k0 * invk * g.x, kn1 = k1 * invk * g.y;
  const float kn2 = k2 * invk * g.z, kn3 = k3 * invk * g.w;

  const float pos = (float)positions[s];
  const float th  = (float)theta_p[0];
  const int idx = d0 & 63, h = d0 >> 6, p0 = idx >> 1;
  const float lg32 = __log2f(th) * (1.0f / 32.0f);
  const float f0 = fast_exp2(-(float)p0 * lg32);
  const float f1 = fast_exp2(-(float)(p0 + 1) * lg32);
  float s0, cc0, s1, cc1;
  __sincosf(pos * f0, &s0, &cc0);
  __sincosf(pos * f1, &s1, &cc1);

  const float qe0 = qn0 * cc0 - qn1 * s0, qo0 = qn1 * cc0 + qn0 * s0;
  const float qe1 = qn2 * cc1 - qn3 * s1, qo1 = qn3 * cc1 + qn2 * s1;
  const float ke0 = kn0 * cc0 - kn1 * s0, ko0 = kn1 * cc0 + kn0 * s0;
  const float ke1 = kn2 * cc1 - kn3 * s1, ko1 = kn3 * cc1 + kn2 * s1;

  const size_t obase = ((size_t)((b * NH + h) * S_LEN + s)) * 64 + idx;
  bf16x4 qo = { (__bf16)qe0, (__bf16)qo0, (__bf16)qe1, (__bf16)qo1 };
  bf16x4 ko = { (__bf16)ke0, (__bf16)ko0, (__bf16)ke1, (__bf16)ko1 };
  *(bf16x4*)(Qh + obase) = qo;
  *(bf16x4*)(Kh + obase) = ko;
}

// ---------------- causal flash attention, balanced + double-buffered + XCD-local ----
__global__ __launch_bounds__(256) void attn_fwd(
    const __bf16* __restrict__ Qh, const __bf16* __restrict__ Kh,
    const __bf16* __restrict__ Vt, __bf16* __restrict__ Ob)
{
  const int bid = blockIdx.x + 16 * blockIdx.y;
  const int px  = bid >> 5;
  const int rr  = bid & 31;
  const int bh  = (rr & 7) * 4 + (rr >> 3);      // same-bh blocks -> same bid%8
  const int tid = threadIdx.x, lane = tid & 63, w = tid >> 6;
  const int lm = lane & 15, qd = lane >> 4;

  __shared__ __align__(16) __bf16 smem[2 * 4096 + 2 * 4096 + 4 * 1152];
  __bf16* Ks = smem;                 // [2][4096]
  __bf16* Vs = smem + 8192;          // [2][4096]
  __bf16* Pw = smem + 16384 + w * 1152;

  const int qtA = px, qtB = 31 - px;
  const int rowA = qtA * 64 + w * 16, rowB = qtB * 64 + w * 16;

  const size_t qbase = (size_t)bh * S_LEN * 64;
  const bf16x8 aqA0 = *(const bf16x8*)(Qh + qbase + (size_t)(rowA + lm) * 64 + qd * 8);
  const bf16x8 aqA1 = *(const bf16x8*)(Qh + qbase + (size_t)(rowA + lm) * 64 + 32 + qd * 8);
  const bf16x8 aqB0 = *(const bf16x8*)(Qh + qbase + (size_t)(rowB + lm) * 64 + qd * 8);
  const bf16x8 aqB1 = *(const bf16x8*)(Qh + qbase + (size_t)(rowB + lm) * 64 + 32 + qd * 8);

  const __bf16* Kb = Kh + (size_t)bh * S_LEN * 64;
  const __bf16* Vb = Vt + (size_t)bh * 64 * S_LEN;
  const int c0 = tid, c1 = 256 + tid;
  const int kr0 = c0 >> 3, kr1 = c1 >> 3;
  const int kg0 = ((c0 & 7) ^ (kr0 & 7)) * 8;
  const int kg1 = ((c1 & 7) ^ (kr1 & 7)) * 8;
  const int cpA = (qd ^ (lm & 7)) * 8;
  const int cpB = cpA ^ 32;

  auto stage = [&](int buf, int k0) {
    __bf16* Kd = Ks + buf * 4096;
    __bf16* Vd = Vs + buf * 4096;
    gld_lds16(Kb + (size_t)(k0 + kr0) * 64 + kg0, &Kd[c0 * 8]);
    gld_lds16(Kb + (size_t)(k0 + kr1) * 64 + kg1, &Kd[c1 * 8]);
    gld_lds16(Vb + (size_t)kr0 * S_LEN + k0 + kg0, &Vd[c0 * 8]);
    gld_lds16(Vb + (size_t)kr1 * S_LEN + k0 + kg1, &Vd[c1 * 8]);
  };

  const float SC2 = 0.125f * 1.44269504089f;   // 1/sqrt(64) * log2(e)
  const float OFF = 12.0f;                     // fixed exponent offset (cancels in norm)
  f32x4 zero = {0.f, 0.f, 0.f, 0.f};
  float l[4];
  f32x4 o[4];

  stage(0, 0);

  const int b = bh >> 4, h = bh & 15;

  for (int it = 0; it < 33; ++it) {
    const int seg = (it > qtA);
    const int kt  = seg ? it - qtA - 1 : it;
    const int qt  = seg ? qtB : qtA;
    const int cur = it & 1;

    if (kt == 0) {
      #pragma unroll
      for (int r = 0; r < 4; r++) l[r] = 0.f;
      #pragma unroll
      for (int jb = 0; jb < 4; jb++) o[jb] = zero;
    }

    __syncthreads();                 // buf[cur] staged; buf[cur^1] free
    if (it + 1 < 33) {
      const int nkt = (it + 1 > qtA) ? it - qtA : it + 1;
      stage(cur ^ 1, nkt * 64);
    }

    const __bf16* Kc = Ks + cur * 4096;
    const __bf16* Vc = Vs + cur * 4096;
    const bf16x8 a0 = seg ? aqB0 : aqA0;
    const bf16x8 a1 = seg ? aqB1 : aqA1;
    const int rowg = (seg ? rowB : rowA) + qd * 4;
    const int k0 = kt * 64;

    float p[4][4];
    const bool diag = (kt == qt);
    #pragma unroll
    for (int kb = 0; kb < 4; kb++) {
      const int krow = (kb * 16 + lm) * 64;
      const bf16x8 bk0 = *(const bf16x8*)&Kc[krow + cpA];
      const bf16x8 bk1 = *(const bf16x8*)&Kc[krow + cpB];
      f32x4 sc = zero;
      sc = __builtin_amdgcn_mfma_f32_16x16x32_bf16(a0, bk0, sc, 0, 0, 0);
      sc = __builtin_amdgcn_mfma_f32_16x16x32_bf16(a1, bk1, sc, 0, 0, 0);
      if (diag) {
        const int colg = k0 + kb * 16 + lm;
        #pragma unroll
        for (int r = 0; r < 4; r++) {
          const float e = fast_exp2(fmaf(sc[r], SC2, -OFF));
          p[kb][r] = (colg <= rowg + r) ? e : 0.f;
          l[r] += p[kb][r];
        }
      } else {
        #pragma unroll
        for (int r = 0; r < 4; r++) {
          p[kb][r] = fast_exp2(fmaf(sc[r], SC2, -OFF));
          l[r] += p[kb][r];
        }
      }
    }

    // P: C-layout -> LDS (stride 72) -> A-layout frags
    #pragma unroll
    for (int kb = 0; kb < 4; kb++)
      #pragma unroll
      for (int r = 0; r < 4; r++)
        Pw[(qd * 4 + r) * 72 + kb * 16 + lm] = (__bf16)p[kb][r];

    const bf16x8 ap0 = *(const bf16x8*)&Pw[lm * 72 + qd * 8];
    const bf16x8 ap1 = *(const bf16x8*)&Pw[lm * 72 + 32 + qd * 8];
    #pragma unroll
    for (int jb = 0; jb < 4; jb++) {
      const int vrow = (jb * 16 + lm) * 64;
      const bf16x8 bv0 = *(const bf16x8*)&Vc[vrow + cpA];
      const bf16x8 bv1 = *(const bf16x8*)&Vc[vrow + cpB];
      o[jb] = __builtin_amdgcn_mfma_f32_16x16x32_bf16(ap1, bv1,
              __builtin_amdgcn_mfma_f32_16x16x32_bf16(ap0, bv0, o[jb], 0, 0, 0), 0, 0, 0);
    }

    if (kt == qt) {                  // segment epilogue
      #pragma unroll
      for (int r = 0; r < 4; r++) {
        float lr = l[r];
        #pragma unroll
        for (int off = 8; off; off >>= 1) lr += __shfl_xor(lr, off);
        const float inv = 1.0f / lr;
        const size_t base = ((size_t)(b * S_LEN + rowg + r)) * D_DIM + h * 64;
        #pragma unroll
        for (int jb = 0; jb < 4; jb++)
          Ob[base + jb * 16 + lm] = (__bf16)(o[jb][r] * inv);
      }
    }
  }
}

extern "C" void kernel_launch(void* const* d_in, const int* in_sizes, int n_in,
                              void* d_out, int out_size, void* d_ws, size_t ws_size,
                              hipStream_t stream)
{
  (void)in_sizes; (void)n_in; (void)out_size; (void)ws_size;
  const float* x    = (const float*)d_in[0];
  const float* WQ   = (const float*)d_in[1];
  const float* WK   = (const float*)d_in[2];
  const float* WV   = (const float*)d_in[3];
  const float* WO   = (const float*)d_in[4];
  const float* gain = (const float*)d_in[5];
  const int* positions = (const int*)d_in[6];
  const int* theta     = (const int*)d_in[7];
  float* out = (float*)d_out;

  char* ws = (char*)d_ws;
  const size_t MB = 1024 * 1024;
  __bf16* xb  = (__bf16*)(ws + 0);        //  8 MB
  __bf16* WQb = (__bf16*)(ws + 8  * MB);  //  2 MB
  __bf16* WKb = (__bf16*)(ws + 10 * MB);  //  2 MB
  __bf16* WVb = (__bf16*)(ws + 12 * MB);  //  2 MB
  __bf16* WOb = (__bf16*)(ws + 14 * MB);  //  2 MB
  __bf16* Qfb = (__bf16*)(ws + 16 * MB);  //  8 MB  Q pre-norm bf16 [4096][1024]
  __bf16* Kfb = (__bf16*)(ws + 24 * MB);  //  8 MB
  __bf16* Vt  = (__bf16*)(ws + 32 * MB);  //  8 MB  [bh][64][s]  (direct from GEMM)
  __bf16* Qh  = (__bf16*)(ws + 40 * MB);  //  8 MB  [bh][s][64]
  __bf16* Kh  = (__bf16*)(ws + 48 * MB);  //  8 MB
  __bf16* Ob  = (__bf16*)(ws + 56 * MB);  //  8 MB  [b][s][1024]

  cast_all<<<1024, 256, 0, stream>>>(x, WQ, WK, WV, WO, xb, WQb, WKb, WVb, WOb);
  gemm_bt<<<dim3(8, 32, 3), 256, 0, stream>>>(xb, WQb, WKb, WVb, Qfb, Kfb, Vt);
  norm_rope<<<4096, 256, 0, stream>>>(Qfb, Kfb, gain, positions, theta, Qh, Kh);
  attn_fwd<<<dim3(16, 32), 256, 0, stream>>>(Qh, Kh, Vt, Ob);
  gemm_out64<<<dim3(8, 64), 256, 0, stream>>>(Ob, WOb, out);
}

// Round 6
// 190.791 us; speedup vs baseline: 1.7877x; 1.0646x over previous
//
#include <hip/hip_runtime.h>
#include <hip/hip_bf16.h>

typedef __attribute__((ext_vector_type(8))) __bf16 bf16x8;
typedef __attribute__((ext_vector_type(4))) __bf16 bf16x4;
typedef __attribute__((ext_vector_type(4))) float  f32x4;

#define S_LEN 2048
#define D_DIM 1024
#define NH    16
#define GK    1024
#define GN    1024

__device__ __forceinline__ float fast_exp2(float x) {
#if __has_builtin(__builtin_amdgcn_exp2f)
  return __builtin_amdgcn_exp2f(x);
#else
  return exp2f(x);
#endif
}

// async global->LDS, 16B per lane; HW scatters to wave-uniform-base + lane*16
__device__ __forceinline__ void gld_lds16(const void* g, void* l) {
  __builtin_amdgcn_global_load_lds(
      (const __attribute__((address_space(1))) unsigned int*)g,
      (__attribute__((address_space(3))) unsigned int*)l, 16, 0, 0);
}

// ---------------- fused fp32 -> bf16 cast, grid-stride ----------------
__global__ __launch_bounds__(256) void cast_all(
    const float* __restrict__ x,  const float* __restrict__ wq, const float* __restrict__ wk,
    const float* __restrict__ wv, const float* __restrict__ wo,
    __bf16* __restrict__ xb, __bf16* __restrict__ wqb, __bf16* __restrict__ wkb,
    __bf16* __restrict__ wvb, __bf16* __restrict__ wob)
{
  const int NTOT = 2 << 20;                      // 2M float4 chunks
  for (int i = blockIdx.x * 256 + threadIdx.x; i < NTOT; i += 1024 * 256) {
    const float* s; __bf16* d; int off;
    if (i < (1 << 20)) { s = x; d = xb; off = i; }
    else {
      const int j = i - (1 << 20);
      const int r = j >> 18; off = j & ((1 << 18) - 1);
      s = (r == 0) ? wq : (r == 1) ? wk : (r == 2) ? wv : wo;
      d = (r == 0) ? wqb : (r == 1) ? wkb : (r == 2) ? wvb : wob;
    }
    float4 v = ((const float4*)s)[off];
    bf16x4 o = { (__bf16)v.x, (__bf16)v.y, (__bf16)v.z, (__bf16)v.w };
    ((bf16x4*)d)[off] = o;
  }
}

// ---------------- GEMM 128x128, BK=64: C[m][n] = sum_k A[m][k]*W[n][k] ----------------
__global__ __launch_bounds__(256) void gemm_bt(
    const __bf16* __restrict__ A,
    const __bf16* __restrict__ W0, const __bf16* __restrict__ W1, const __bf16* __restrict__ W2,
    __bf16* __restrict__ C0, __bf16* __restrict__ C1, __bf16* __restrict__ VtOut)
{
  const int mode = blockIdx.z;
  const __bf16* Wm = (mode == 0) ? W0 : (mode == 1) ? W1 : W2;

  __shared__ __align__(16) __bf16 As[128 * 64];   // 16 KB
  __shared__ __align__(16) __bf16 Bs[128 * 64];   // 16 KB

  const int tid  = threadIdx.x;
  const int lane = tid & 63;
  const int w    = tid >> 6;
  const int wr   = w >> 1, wc = w & 1;
  const int lm   = lane & 15, qd = lane >> 4;
  const int m0 = blockIdx.y * 128, n0 = blockIdx.x * 128;

  const __bf16* ap[4]; const __bf16* bp[4]; int lo[4];
  #pragma unroll
  for (int j = 0; j < 4; j++) {
    const int c = tid + 256 * j;
    const int r = c >> 3, cpos = c & 7;
    const int g = (cpos ^ (r & 7)) * 8;
    ap[j] = A  + (size_t)(m0 + r) * GK + g;
    bp[j] = Wm + (size_t)(n0 + r) * GK + g;
    lo[j] = c * 8;
  }

  const int sw = lm & 7;

  f32x4 zero = {0.f, 0.f, 0.f, 0.f};
  f32x4 acc[4][4];
  #pragma unroll
  for (int i = 0; i < 4; i++)
    #pragma unroll
    for (int j = 0; j < 4; j++) acc[i][j] = zero;

  for (int k0 = 0; k0 < GK; k0 += 64) {
    #pragma unroll
    for (int j = 0; j < 4; j++) {
      gld_lds16(ap[j] + k0, &As[lo[j]]);
      gld_lds16(bp[j] + k0, &Bs[lo[j]]);
    }
    __syncthreads();
    #pragma unroll
    for (int half = 0; half < 2; half++) {
      const int cph = ((qd + 4 * half) ^ sw) * 8;
      bf16x8 af[4], bfv[4];
      #pragma unroll
      for (int i = 0; i < 4; i++) af[i]  = *(const bf16x8*)&As[(wr * 64 + i * 16 + lm) * 64 + cph];
      #pragma unroll
      for (int j = 0; j < 4; j++) bfv[j] = *(const bf16x8*)&Bs[(wc * 64 + j * 16 + lm) * 64 + cph];
      #pragma unroll
      for (int i = 0; i < 4; i++)
        #pragma unroll
        for (int j = 0; j < 4; j++)
          acc[i][j] = __builtin_amdgcn_mfma_f32_16x16x32_bf16(af[i], bfv[j], acc[i][j], 0, 0, 0);
    }
    __syncthreads();
  }

  if (mode < 2) {
    __bf16* C = (mode == 0) ? C0 : C1;
    #pragma unroll
    for (int i = 0; i < 4; i++) {
      const int row = m0 + wr * 64 + i * 16 + qd * 4;
      #pragma unroll
      for (int j = 0; j < 4; j++) {
        const int col = n0 + wc * 64 + j * 16 + lm;
        #pragma unroll
        for (int r = 0; r < 4; r++)
          C[(size_t)(row + r) * GN + col] = (__bf16)acc[i][j][r];
      }
    }
  } else {
    #pragma unroll
    for (int i = 0; i < 4; i++) {
      const int row = m0 + wr * 64 + i * 16 + qd * 4;    // token
      const int b = row >> 11, s = row & (S_LEN - 1);
      #pragma unroll
      for (int j = 0; j < 4; j++) {
        const int col = n0 + wc * 64 + j * 16 + lm;      // vdim
        const int h = col >> 6, d = col & 63;
        bf16x4 o = { (__bf16)acc[i][j][0], (__bf16)acc[i][j][1],
                     (__bf16)acc[i][j][2], (__bf16)acc[i][j][3] };
        *(bf16x4*)(VtOut + (((size_t)(b * NH + h) * 64 + d) * S_LEN + s)) = o;
      }
    }
  }
}

// ---------------- GEMM 64x128, BK=64 (fp32 out): out-projection ----------------
__global__ __launch_bounds__(256) void gemm_out64(
    const __bf16* __restrict__ A, const __bf16* __restrict__ Wm, float* __restrict__ C)
{
  __shared__ __align__(16) __bf16 As[64 * 64];    //  8 KB
  __shared__ __align__(16) __bf16 Bs[128 * 64];   // 16 KB

  const int tid  = threadIdx.x;
  const int lane = tid & 63;
  const int w    = tid >> 6;
  const int wr   = w >> 1, wc = w & 1;
  const int lm   = lane & 15, qd = lane >> 4;
  const int m0 = blockIdx.y * 64, n0 = blockIdx.x * 128;

  const __bf16* ap[2]; int loA[2];
  #pragma unroll
  for (int j = 0; j < 2; j++) {
    const int c = tid + 256 * j;
    const int r = c >> 3, cpos = c & 7;
    ap[j] = A + (size_t)(m0 + r) * GK + (cpos ^ (r & 7)) * 8;
    loA[j] = c * 8;
  }
  const __bf16* bp[4]; int loB[4];
  #pragma unroll
  for (int j = 0; j < 4; j++) {
    const int c = tid + 256 * j;
    const int r = c >> 3, cpos = c & 7;
    bp[j] = Wm + (size_t)(n0 + r) * GK + (cpos ^ (r & 7)) * 8;
    loB[j] = c * 8;
  }

  const int sw = lm & 7;

  f32x4 zero = {0.f, 0.f, 0.f, 0.f};
  f32x4 acc[2][4];
  #pragma unroll
  for (int i = 0; i < 2; i++)
    #pragma unroll
    for (int j = 0; j < 4; j++) acc[i][j] = zero;

  for (int k0 = 0; k0 < GK; k0 += 64) {
    #pragma unroll
    for (int j = 0; j < 2; j++) gld_lds16(ap[j] + k0, &As[loA[j]]);
    #pragma unroll
    for (int j = 0; j < 4; j++) gld_lds16(bp[j] + k0, &Bs[loB[j]]);
    __syncthreads();
    #pragma unroll
    for (int half = 0; half < 2; half++) {
      const int cph = ((qd + 4 * half) ^ sw) * 8;
      bf16x8 af[2], bfv[4];
      #pragma unroll
      for (int i = 0; i < 2; i++) af[i]  = *(const bf16x8*)&As[(wr * 32 + i * 16 + lm) * 64 + cph];
      #pragma unroll
      for (int j = 0; j < 4; j++) bfv[j] = *(const bf16x8*)&Bs[(wc * 64 + j * 16 + lm) * 64 + cph];
      #pragma unroll
      for (int i = 0; i < 2; i++)
        #pragma unroll
        for (int j = 0; j < 4; j++)
          acc[i][j] = __builtin_amdgcn_mfma_f32_16x16x32_bf16(af[i], bfv[j], acc[i][j], 0, 0, 0);
    }
    __syncthreads();
  }

  #pragma unroll
  for (int i = 0; i < 2; i++) {
    const int row = m0 + wr * 32 + i * 16 + qd * 4;
    #pragma unroll
    for (int j = 0; j < 4; j++) {
      const int col = n0 + wc * 64 + j * 16 + lm;
      #pragma unroll
      for (int r = 0; r < 4; r++)
        C[(size_t)(row + r) * GN + col] = acc[i][j][r];
    }
  }
}

// ---------------- RMSNorm + RoPE + head split (Q,K only; bf16 in) ----------------
__global__ __launch_bounds__(256) void norm_rope(
    const __bf16* __restrict__ Qf, const __bf16* __restrict__ Kf,
    const float* __restrict__ gain, const int* __restrict__ positions,
    const int* __restrict__ theta_p,
    __bf16* __restrict__ Qh, __bf16* __restrict__ Kh)
{
  const int row = blockIdx.x;             // b*S + s
  const int s = row & (S_LEN - 1), b = row >> 11;
  const int t = threadIdx.x, d0 = t * 4;

  const bf16x4 qv = *(const bf16x4*)(Qf + (size_t)row * D_DIM + d0);
  const bf16x4 kv = *(const bf16x4*)(Kf + (size_t)row * D_DIM + d0);
  const float q0 = (float)qv[0], q1 = (float)qv[1], q2 = (float)qv[2], q3 = (float)qv[3];
  const float k0 = (float)kv[0], k1 = (float)kv[1], k2 = (float)kv[2], k3 = (float)kv[3];

  float sq = q0 * q0 + q1 * q1 + q2 * q2 + q3 * q3;
  float sk = k0 * k0 + k1 * k1 + k2 * k2 + k3 * k3;
  #pragma unroll
  for (int off = 32; off; off >>= 1) { sq += __shfl_xor(sq, off); sk += __shfl_xor(sk, off); }
  __shared__ float red[8];
  const int lane = t & 63, wv = t >> 6;
  if (lane == 0) { red[wv] = sq; red[4 + wv] = sk; }
  __syncthreads();
  sq = red[0] + red[1] + red[2] + red[3];
  sk = red[4] + red[5] + red[6] + red[7];
  const float invq = rsqrtf(sq * (1.0f / 1024.0f) + 1e-5f);
  const float invk = rsqrtf(sk * (1.0f / 1024.0f) + 1e-5f);

  const float4 g = *(const float4*)(gain + d0);
  const float qn0 = q0 * invq * g.x, qn1 = q1 * invq * g.y;
  const float qn2 = q2 * invq * g.z, qn3 = q3 * invq * g.w;
  const float kn0 = k0 * invk * g.x, kn1 = k1 * invk * g.y;
  const float kn2 = k2 * invk * g.z, kn3 = k3 * invk * g.w;

  const float pos = (float)positions[s];
  const float th  = (float)theta_p[0];
  const int idx = d0 & 63, h = d0 >> 6, p0 = idx >> 1;
  const float lg32 = __log2f(th) * (1.0f / 32.0f);
  const float f0 = fast_exp2(-(float)p0 * lg32);
  const float f1 = fast_exp2(-(float)(p0 + 1) * lg32);
  float s0, cc0, s1, cc1;
  __sincosf(pos * f0, &s0, &cc0);
  __sincosf(pos * f1, &s1, &cc1);

  const float qe0 = qn0 * cc0 - qn1 * s0, qo0 = qn1 * cc0 + qn0 * s0;
  const float qe1 = qn2 * cc1 - qn3 * s1, qo1 = qn3 * cc1 + qn2 * s1;
  const float ke0 = kn0 * cc0 - kn1 * s0, ko0 = kn1 * cc0 + kn0 * s0;
  const float ke1 = kn2 * cc1 - kn3 * s1, ko1 = kn3 * cc1 + kn2 * s1;

  const size_t obase = ((size_t)((b * NH + h) * S_LEN + s)) * 64 + idx;
  bf16x4 qo = { (__bf16)qe0, (__bf16)qo0, (__bf16)qe1, (__bf16)qo1 };
  bf16x4 ko = { (__bf16)ke0, (__bf16)ko0, (__bf16)ke1, (__bf16)ko1 };
  *(bf16x4*)(Qh + obase) = qo;
  *(bf16x4*)(Kh + obase) = ko;
}

// ---------------- causal flash attention, 1024 blocks @ 4/CU ----------------
// One 64-row q-tile per block (kt=0..qt). LDS = 40960 B exactly -> 4 blocks/CU.
// qt ordering: co-resident bids {c,256+c,512+c,768+c} get qts {31-j, j, 23-j, 8+j}
// (sum 62+4 iters -> per-CU balanced), heavy tiles dispatched first.
// P scratch: stride-64 XOR-chunk swizzle (same family as K/V) - no pad needed.
__global__ __launch_bounds__(256) void attn_fwd(
    const __bf16* __restrict__ Qh, const __bf16* __restrict__ Kh,
    const __bf16* __restrict__ Vt, __bf16* __restrict__ Ob)
{
  const int bid = blockIdx.x;
  const int g   = bid >> 5, gj = g & 7, gs = g >> 3;
  const int qt  = (gs == 0) ? 31 - gj : (gs == 1) ? gj : (gs == 2) ? 23 - gj : 8 + gj;
  const int rr  = bid & 31;
  const int bh  = (rr & 7) * 4 + (rr >> 3);      // same-bh blocks -> same bid%8 (XCD)
  const int tid = threadIdx.x, lane = tid & 63, w = tid >> 6;
  const int lm = lane & 15, qd = lane >> 4;

  __shared__ __align__(16) __bf16 smem[8192 + 8192 + 4096];   // 40960 B
  __bf16* Ks = smem;                 // [2][4096]
  __bf16* Vs = smem + 8192;          // [2][4096]
  __bf16* Pw = smem + 16384 + w * 1024;

  const int row0 = qt * 64 + w * 16;
  const size_t qbase = (size_t)bh * S_LEN * 64;
  const bf16x8 aq0 = *(const bf16x8*)(Qh + qbase + (size_t)(row0 + lm) * 64 + qd * 8);
  const bf16x8 aq1 = *(const bf16x8*)(Qh + qbase + (size_t)(row0 + lm) * 64 + 32 + qd * 8);

  const __bf16* Kb = Kh + (size_t)bh * S_LEN * 64;
  const __bf16* Vb = Vt + (size_t)bh * 64 * S_LEN;
  const int c0 = tid, c1 = 256 + tid;
  const int kr0 = c0 >> 3, kr1 = c1 >> 3;
  const int kg0 = ((c0 & 7) ^ (kr0 & 7)) * 8;
  const int kg1 = ((c1 & 7) ^ (kr1 & 7)) * 8;
  const int cpA = (qd ^ (lm & 7)) * 8;   // frag chunk, shared by K/V tiles and P
  const int cpB = cpA ^ 32;

  auto stage = [&](int buf, int k0) {
    __bf16* Kd = Ks + buf * 4096;
    __bf16* Vd = Vs + buf * 4096;
    gld_lds16(Kb + (size_t)(k0 + kr0) * 64 + kg0, &Kd[c0 * 8]);
    gld_lds16(Kb + (size_t)(k0 + kr1) * 64 + kg1, &Kd[c1 * 8]);
    gld_lds16(Vb + (size_t)kr0 * S_LEN + k0 + kg0, &Vd[c0 * 8]);
    gld_lds16(Vb + (size_t)kr1 * S_LEN + k0 + kg1, &Vd[c1 * 8]);
  };

  const float SC2 = 0.125f * 1.44269504089f;   // 1/sqrt(64) * log2(e)
  const float OFF = 12.0f;                     // fixed exponent offset (cancels in norm)
  f32x4 zero = {0.f, 0.f, 0.f, 0.f};
  float l[4] = {0.f, 0.f, 0.f, 0.f};
  f32x4 o[4];
  #pragma unroll
  for (int jb = 0; jb < 4; jb++) o[jb] = zero;

  stage(0, 0);

  const int rowg = row0 + qd * 4;
  const int pxor = qd * 4;                      // base P row for this quad

  for (int kt = 0; kt <= qt; ++kt) {
    const int cur = kt & 1;
    __syncthreads();                 // buf[cur] staged; buf[cur^1] free
    if (kt < qt) stage(cur ^ 1, (kt + 1) * 64);

    const __bf16* Kc = Ks + cur * 4096;
    const __bf16* Vc = Vs + cur * 4096;
    const int k0 = kt * 64;

    float p[4][4];
    const bool diag = (kt == qt);
    #pragma unroll
    for (int kb = 0; kb < 4; kb++) {
      const int krow = (kb * 16 + lm) * 64;
      const bf16x8 bk0 = *(const bf16x8*)&Kc[krow + cpA];
      const bf16x8 bk1 = *(const bf16x8*)&Kc[krow + cpB];
      f32x4 sc = zero;
      sc = __builtin_amdgcn_mfma_f32_16x16x32_bf16(aq0, bk0, sc, 0, 0, 0);
      sc = __builtin_amdgcn_mfma_f32_16x16x32_bf16(aq1, bk1, sc, 0, 0, 0);
      if (diag) {
        const int colg = k0 + kb * 16 + lm;
        #pragma unroll
        for (int r = 0; r < 4; r++) {
          const float e = fast_exp2(fmaf(sc[r], SC2, -OFF));
          p[kb][r] = (colg <= rowg + r) ? e : 0.f;
          l[r] += p[kb][r];
        }
      } else {
        #pragma unroll
        for (int r = 0; r < 4; r++) {
          p[kb][r] = fast_exp2(fmaf(sc[r], SC2, -OFF));
          l[r] += p[kb][r];
        }
      }
    }

    // P: C-layout -> LDS (stride-64, XOR-chunk swizzled) -> A-layout frags
    #pragma unroll
    for (int kb = 0; kb < 4; kb++) {
      const int cb = kb * 2 + (lm >> 3), wi = lm & 7;
      #pragma unroll
      for (int r = 0; r < 4; r++) {
        const int prow = pxor + r;
        Pw[prow * 64 + ((cb ^ (prow & 7)) << 3) + wi] = (__bf16)p[kb][r];
      }
    }

    const bf16x8 ap0 = *(const bf16x8*)&Pw[lm * 64 + cpA];
    const bf16x8 ap1 = *(const bf16x8*)&Pw[lm * 64 + cpB];
    #pragma unroll
    for (int jb = 0; jb < 4; jb++) {
      const int vrow = (jb * 16 + lm) * 64;
      const bf16x8 bv0 = *(const bf16x8*)&Vc[vrow + cpA];
      const bf16x8 bv1 = *(const bf16x8*)&Vc[vrow + cpB];
      o[jb] = __builtin_amdgcn_mfma_f32_16x16x32_bf16(ap1, bv1,
              __builtin_amdgcn_mfma_f32_16x16x32_bf16(ap0, bv0, o[jb], 0, 0, 0), 0, 0, 0);
    }
  }

  const int b = bh >> 4, h = bh & 15;
  #pragma unroll
  for (int r = 0; r < 4; r++) {
    float lr = l[r];
    #pragma unroll
    for (int off = 8; off; off >>= 1) lr += __shfl_xor(lr, off);
    const float inv = 1.0f / lr;
    const size_t base = ((size_t)(b * S_LEN + rowg + r)) * D_DIM + h * 64;
    #pragma unroll
    for (int jb = 0; jb < 4; jb++)
      Ob[base + jb * 16 + lm] = (__bf16)(o[jb][r] * inv);
  }
}

extern "C" void kernel_launch(void* const* d_in, const int* in_sizes, int n_in,
                              void* d_out, int out_size, void* d_ws, size_t ws_size,
                              hipStream_t stream)
{
  (void)in_sizes; (void)n_in; (void)out_size; (void)ws_size;
  const float* x    = (const float*)d_in[0];
  const float* WQ   = (const float*)d_in[1];
  const float* WK   = (const float*)d_in[2];
  const float* WV   = (const float*)d_in[3];
  const float* WO   = (const float*)d_in[4];
  const float* gain = (const float*)d_in[5];
  const int* positions = (const int*)d_in[6];
  const int* theta     = (const int*)d_in[7];
  float* out = (float*)d_out;

  char* ws = (char*)d_ws;
  const size_t MB = 1024 * 1024;
  __bf16* xb  = (__bf16*)(ws + 0);        //  8 MB
  __bf16* WQb = (__bf16*)(ws + 8  * MB);  //  2 MB
  __bf16* WKb = (__bf16*)(ws + 10 * MB);  //  2 MB
  __bf16* WVb = (__bf16*)(ws + 12 * MB);  //  2 MB
  __bf16* WOb = (__bf16*)(ws + 14 * MB);  //  2 MB
  __bf16* Qfb = (__bf16*)(ws + 16 * MB);  //  8 MB  Q pre-norm bf16 [4096][1024]
  __bf16* Kfb = (__bf16*)(ws + 24 * MB);  //  8 MB
  __bf16* Vt  = (__bf16*)(ws + 32 * MB);  //  8 MB  [bh][64][s]  (direct from GEMM)
  __bf16* Qh  = (__bf16*)(ws + 40 * MB);  //  8 MB  [bh][s][64]
  __bf16* Kh  = (__bf16*)(ws + 48 * MB);  //  8 MB
  __bf16* Ob  = (__bf16*)(ws + 56 * MB);  //  8 MB  [b][s][1024]

  cast_all<<<1024, 256, 0, stream>>>(x, WQ, WK, WV, WO, xb, WQb, WKb, WVb, WOb);
  gemm_bt<<<dim3(8, 32, 3), 256, 0, stream>>>(xb, WQb, WKb, WVb, Qfb, Kfb, Vt);
  norm_rope<<<4096, 256, 0, stream>>>(Qfb, Kfb, gain, positions, theta, Qh, Kh);
  attn_fwd<<<1024, 256, 0, stream>>>(Qh, Kh, Vt, Ob);
  gemm_out64<<<dim3(8, 64), 256, 0, stream>>>(Ob, WOb, out);
}

// Round 7
// 178.549 us; speedup vs baseline: 1.9102x; 1.0686x over previous
//
#include <hip/hip_runtime.h>
#include <hip/hip_bf16.h>

typedef __attribute__((ext_vector_type(8))) __bf16 bf16x8;
typedef __attribute__((ext_vector_type(4))) __bf16 bf16x4;
typedef __attribute__((ext_vector_type(4))) float  f32x4;

#define S_LEN 2048
#define D_DIM 1024
#define NH    16
#define GK    1024
#define GN    1024

__device__ __forceinline__ float fast_exp2(float x) {
#if __has_builtin(__builtin_amdgcn_exp2f)
  return __builtin_amdgcn_exp2f(x);
#else
  return exp2f(x);
#endif
}

// async global->LDS, 16B per lane; HW scatters to wave-uniform-base + lane*16
__device__ __forceinline__ void gld_lds16(const void* g, void* l) {
  __builtin_amdgcn_global_load_lds(
      (const __attribute__((address_space(1))) unsigned int*)g,
      (__attribute__((address_space(3))) unsigned int*)l, 16, 0, 0);
}

// ---------------- fused fp32 -> bf16 cast, grid-stride ----------------
__global__ __launch_bounds__(256) void cast_all(
    const float* __restrict__ x,  const float* __restrict__ wq, const float* __restrict__ wk,
    const float* __restrict__ wv, const float* __restrict__ wo,
    __bf16* __restrict__ xb, __bf16* __restrict__ wqb, __bf16* __restrict__ wkb,
    __bf16* __restrict__ wvb, __bf16* __restrict__ wob)
{
  const int NTOT = 2 << 20;                      // 2M float4 chunks
  for (int i = blockIdx.x * 256 + threadIdx.x; i < NTOT; i += 1024 * 256) {
    const float* s; __bf16* d; int off;
    if (i < (1 << 20)) { s = x; d = xb; off = i; }
    else {
      const int j = i - (1 << 20);
      const int r = j >> 18; off = j & ((1 << 18) - 1);
      s = (r == 0) ? wq : (r == 1) ? wk : (r == 2) ? wv : wo;
      d = (r == 0) ? wqb : (r == 1) ? wkb : (r == 2) ? wvb : wob;
    }
    float4 v = ((const float4*)s)[off];
    bf16x4 o = { (__bf16)v.x, (__bf16)v.y, (__bf16)v.z, (__bf16)v.w };
    ((bf16x4*)d)[off] = o;
  }
}

// ---------------- QKV GEMM 64x128, BK=64, XCD-partitioned ----------------
// 1536 blocks = 6/CU (LDS 24 KB, lb(256,6)). bid%8 = XCD region (mg,ng):
// XCD covers m-tiles [mg*16,mg*16+16) x n-tiles [ng*4,ng*4+4) x all 3 z.
// z varies fastest among same-XCD bids -> same-(m,n) blocks share A in L2.
// mode 0/1: bf16 C row-major (Q/K pre-norm). mode 2: bf16 direct to Vt [bh][d][s].
__global__ __launch_bounds__(256, 6) void gemm_qkv(
    const __bf16* __restrict__ A,
    const __bf16* __restrict__ W0, const __bf16* __restrict__ W1, const __bf16* __restrict__ W2,
    __bf16* __restrict__ C0, __bf16* __restrict__ C1, __bf16* __restrict__ VtOut)
{
  const int bid = blockIdx.x;
  const int e = bid & 7, mg = e >> 1, ng = e & 1;
  const int q = bid >> 3;              // 0..191
  const int mode = q % 3;
  const int t = q / 3;                 // 0..63
  const int m0 = (mg * 16 + (t & 15)) * 64;
  const int n0 = (ng * 4 + (t >> 4)) * 128;
  const __bf16* Wm = (mode == 0) ? W0 : (mode == 1) ? W1 : W2;

  __shared__ __align__(16) __bf16 As[64 * 64];    //  8 KB
  __shared__ __align__(16) __bf16 Bs[128 * 64];   // 16 KB

  const int tid  = threadIdx.x;
  const int lane = tid & 63;
  const int w    = tid >> 6;
  const int wr   = w >> 1, wc = w & 1;
  const int lm   = lane & 15, qd = lane >> 4;

  const __bf16* ap[2]; int loA[2];
  #pragma unroll
  for (int j = 0; j < 2; j++) {
    const int c = tid + 256 * j;
    const int r = c >> 3, cpos = c & 7;
    ap[j] = A + (size_t)(m0 + r) * GK + (cpos ^ (r & 7)) * 8;
    loA[j] = c * 8;
  }
  const __bf16* bp[4]; int loB[4];
  #pragma unroll
  for (int j = 0; j < 4; j++) {
    const int c = tid + 256 * j;
    const int r = c >> 3, cpos = c & 7;
    bp[j] = Wm + (size_t)(n0 + r) * GK + (cpos ^ (r & 7)) * 8;
    loB[j] = c * 8;
  }

  const int sw = lm & 7;

  f32x4 zero = {0.f, 0.f, 0.f, 0.f};
  f32x4 acc[2][4];
  #pragma unroll
  for (int i = 0; i < 2; i++)
    #pragma unroll
    for (int j = 0; j < 4; j++) acc[i][j] = zero;

  for (int k0 = 0; k0 < GK; k0 += 64) {
    #pragma unroll
    for (int j = 0; j < 2; j++) gld_lds16(ap[j] + k0, &As[loA[j]]);
    #pragma unroll
    for (int j = 0; j < 4; j++) gld_lds16(bp[j] + k0, &Bs[loB[j]]);
    __syncthreads();
    #pragma unroll
    for (int half = 0; half < 2; half++) {
      const int cph = ((qd + 4 * half) ^ sw) * 8;
      bf16x8 af[2], bfv[4];
      #pragma unroll
      for (int i = 0; i < 2; i++) af[i]  = *(const bf16x8*)&As[(wr * 32 + i * 16 + lm) * 64 + cph];
      #pragma unroll
      for (int j = 0; j < 4; j++) bfv[j] = *(const bf16x8*)&Bs[(wc * 64 + j * 16 + lm) * 64 + cph];
      #pragma unroll
      for (int i = 0; i < 2; i++)
        #pragma unroll
        for (int j = 0; j < 4; j++)
          acc[i][j] = __builtin_amdgcn_mfma_f32_16x16x32_bf16(af[i], bfv[j], acc[i][j], 0, 0, 0);
    }
    __syncthreads();
  }

  if (mode < 2) {
    __bf16* C = (mode == 0) ? C0 : C1;
    #pragma unroll
    for (int i = 0; i < 2; i++) {
      const int row = m0 + wr * 32 + i * 16 + qd * 4;
      #pragma unroll
      for (int j = 0; j < 4; j++) {
        const int col = n0 + wc * 64 + j * 16 + lm;
        #pragma unroll
        for (int r = 0; r < 4; r++)
          C[(size_t)(row + r) * GN + col] = (__bf16)acc[i][j][r];
      }
    }
  } else {
    #pragma unroll
    for (int i = 0; i < 2; i++) {
      const int row = m0 + wr * 32 + i * 16 + qd * 4;    // token
      const int b = row >> 11, s = row & (S_LEN - 1);
      #pragma unroll
      for (int j = 0; j < 4; j++) {
        const int col = n0 + wc * 64 + j * 16 + lm;      // vdim
        const int h = col >> 6, d = col & 63;
        bf16x4 o = { (__bf16)acc[i][j][0], (__bf16)acc[i][j][1],
                     (__bf16)acc[i][j][2], (__bf16)acc[i][j][3] };
        *(bf16x4*)(VtOut + (((size_t)(b * NH + h) * 64 + d) * S_LEN + s)) = o;
      }
    }
  }
}

// ---------------- out-proj GEMM 64x128, BK=64, XCD-partitioned (fp32 out) ----------
__global__ __launch_bounds__(256, 6) void gemm_out64(
    const __bf16* __restrict__ A, const __bf16* __restrict__ Wm, float* __restrict__ C)
{
  const int bid = blockIdx.x;          // 512
  const int e = bid & 7, mg = e >> 1, ng = e & 1;
  const int q = bid >> 3;              // 0..63
  const int m0 = (mg * 16 + (q & 15)) * 64;
  const int n0 = (ng * 4 + (q >> 4)) * 128;

  __shared__ __align__(16) __bf16 As[64 * 64];    //  8 KB
  __shared__ __align__(16) __bf16 Bs[128 * 64];   // 16 KB

  const int tid  = threadIdx.x;
  const int lane = tid & 63;
  const int w    = tid >> 6;
  const int wr   = w >> 1, wc = w & 1;
  const int lm   = lane & 15, qd = lane >> 4;

  const __bf16* ap[2]; int loA[2];
  #pragma unroll
  for (int j = 0; j < 2; j++) {
    const int c = tid + 256 * j;
    const int r = c >> 3, cpos = c & 7;
    ap[j] = A + (size_t)(m0 + r) * GK + (cpos ^ (r & 7)) * 8;
    loA[j] = c * 8;
  }
  const __bf16* bp[4]; int loB[4];
  #pragma unroll
  for (int j = 0; j < 4; j++) {
    const int c = tid + 256 * j;
    const int r = c >> 3, cpos = c & 7;
    bp[j] = Wm + (size_t)(n0 + r) * GK + (cpos ^ (r & 7)) * 8;
    loB[j] = c * 8;
  }

  const int sw = lm & 7;

  f32x4 zero = {0.f, 0.f, 0.f, 0.f};
  f32x4 acc[2][4];
  #pragma unroll
  for (int i = 0; i < 2; i++)
    #pragma unroll
    for (int j = 0; j < 4; j++) acc[i][j] = zero;

  for (int k0 = 0; k0 < GK; k0 += 64) {
    #pragma unroll
    for (int j = 0; j < 2; j++) gld_lds16(ap[j] + k0, &As[loA[j]]);
    #pragma unroll
    for (int j = 0; j < 4; j++) gld_lds16(bp[j] + k0, &Bs[loB[j]]);
    __syncthreads();
    #pragma unroll
    for (int half = 0; half < 2; half++) {
      const int cph = ((qd + 4 * half) ^ sw) * 8;
      bf16x8 af[2], bfv[4];
      #pragma unroll
      for (int i = 0; i < 2; i++) af[i]  = *(const bf16x8*)&As[(wr * 32 + i * 16 + lm) * 64 + cph];
      #pragma unroll
      for (int j = 0; j < 4; j++) bfv[j] = *(const bf16x8*)&Bs[(wc * 64 + j * 16 + lm) * 64 + cph];
      #pragma unroll
      for (int i = 0; i < 2; i++)
        #pragma unroll
        for (int j = 0; j < 4; j++)
          acc[i][j] = __builtin_amdgcn_mfma_f32_16x16x32_bf16(af[i], bfv[j], acc[i][j], 0, 0, 0);
    }
    __syncthreads();
  }

  #pragma unroll
  for (int i = 0; i < 2; i++) {
    const int row = m0 + wr * 32 + i * 16 + qd * 4;
    #pragma unroll
    for (int j = 0; j < 4; j++) {
      const int col = n0 + wc * 64 + j * 16 + lm;
      #pragma unroll
      for (int r = 0; r < 4; r++)
        C[(size_t)(row + r) * GN + col] = acc[i][j][r];
    }
  }
}

// ---------------- RMSNorm + RoPE + head split (Q,K only; bf16 in) ----------------
__global__ __launch_bounds__(256) void norm_rope(
    const __bf16* __restrict__ Qf, const __bf16* __restrict__ Kf,
    const float* __restrict__ gain, const int* __restrict__ positions,
    const int* __restrict__ theta_p,
    __bf16* __restrict__ Qh, __bf16* __restrict__ Kh)
{
  const int row = blockIdx.x;             // b*S + s
  const int s = row & (S_LEN - 1), b = row >> 11;
  const int t = threadIdx.x, d0 = t * 4;

  const bf16x4 qv = *(const bf16x4*)(Qf + (size_t)row * D_DIM + d0);
  const bf16x4 kv = *(const bf16x4*)(Kf + (size_t)row * D_DIM + d0);
  const float q0 = (float)qv[0], q1 = (float)qv[1], q2 = (float)qv[2], q3 = (float)qv[3];
  const float k0 = (float)kv[0], k1 = (float)kv[1], k2 = (float)kv[2], k3 = (float)kv[3];

  float sq = q0 * q0 + q1 * q1 + q2 * q2 + q3 * q3;
  float sk = k0 * k0 + k1 * k1 + k2 * k2 + k3 * k3;
  #pragma unroll
  for (int off = 32; off; off >>= 1) { sq += __shfl_xor(sq, off); sk += __shfl_xor(sk, off); }
  __shared__ float red[8];
  const int lane = t & 63, wv = t >> 6;
  if (lane == 0) { red[wv] = sq; red[4 + wv] = sk; }
  __syncthreads();
  sq = red[0] + red[1] + red[2] + red[3];
  sk = red[4] + red[5] + red[6] + red[7];
  const float invq = rsqrtf(sq * (1.0f / 1024.0f) + 1e-5f);
  const float invk = rsqrtf(sk * (1.0f / 1024.0f) + 1e-5f);

  const float4 g = *(const float4*)(gain + d0);
  const float qn0 = q0 * invq * g.x, qn1 = q1 * invq * g.y;
  const float qn2 = q2 * invq * g.z, qn3 = q3 * invq * g.w;
  const float kn0 = k0 * invk * g.x, kn1 = k1 * invk * g.y;
  const float kn2 = k2 * invk * g.z, kn3 = k3 * invk * g.w;

  const float pos = (float)positions[s];
  const float th  = (float)theta_p[0];
  const int idx = d0 & 63, h = d0 >> 6, p0 = idx >> 1;
  const float lg32 = __log2f(th) * (1.0f / 32.0f);
  const float f0 = fast_exp2(-(float)p0 * lg32);
  const float f1 = fast_exp2(-(float)(p0 + 1) * lg32);
  float s0, cc0, s1, cc1;
  __sincosf(pos * f0, &s0, &cc0);
  __sincosf(pos * f1, &s1, &cc1);

  const float qe0 = qn0 * cc0 - qn1 * s0, qo0 = qn1 * cc0 + qn0 * s0;
  const float qe1 = qn2 * cc1 - qn3 * s1, qo1 = qn3 * cc1 + qn2 * s1;
  const float ke0 = kn0 * cc0 - kn1 * s0, ko0 = kn1 * cc0 + kn0 * s0;
  const float ke1 = kn2 * cc1 - kn3 * s1, ko1 = kn3 * cc1 + kn2 * s1;

  const size_t obase = ((size_t)((b * NH + h) * S_LEN + s)) * 64 + idx;
  bf16x4 qo = { (__bf16)qe0, (__bf16)qo0, (__bf16)qe1, (__bf16)qo1 };
  bf16x4 ko = { (__bf16)ke0, (__bf16)ko0, (__bf16)ke1, (__bf16)ko1 };
  *(bf16x4*)(Qh + obase) = qo;
  *(bf16x4*)(Kh + obase) = ko;
}

// ---------------- causal flash attention, 1024 blocks @ 4/CU ----------------
__global__ __launch_bounds__(256) void attn_fwd(
    const __bf16* __restrict__ Qh, const __bf16* __restrict__ Kh,
    const __bf16* __restrict__ Vt, __bf16* __restrict__ Ob)
{
  const int bid = blockIdx.x;
  const int g   = bid >> 5, gj = g & 7, gs = g >> 3;
  const int qt  = (gs == 0) ? 31 - gj : (gs == 1) ? gj : (gs == 2) ? 23 - gj : 8 + gj;
  const int rr  = bid & 31;
  const int bh  = (rr & 7) * 4 + (rr >> 3);      // same-bh blocks -> same bid%8 (XCD)
  const int tid = threadIdx.x, lane = tid & 63, w = tid >> 6;
  const int lm = lane & 15, qd = lane >> 4;

  __shared__ __align__(16) __bf16 smem[8192 + 8192 + 4096];   // 40960 B
  __bf16* Ks = smem;                 // [2][4096]
  __bf16* Vs = smem + 8192;          // [2][4096]
  __bf16* Pw = smem + 16384 + w * 1024;

  const int row0 = qt * 64 + w * 16;
  const size_t qbase = (size_t)bh * S_LEN * 64;
  const bf16x8 aq0 = *(const bf16x8*)(Qh + qbase + (size_t)(row0 + lm) * 64 + qd * 8);
  const bf16x8 aq1 = *(const bf16x8*)(Qh + qbase + (size_t)(row0 + lm) * 64 + 32 + qd * 8);

  const __bf16* Kb = Kh + (size_t)bh * S_LEN * 64;
  const __bf16* Vb = Vt + (size_t)bh * 64 * S_LEN;
  const int c0 = tid, c1 = 256 + tid;
  const int kr0 = c0 >> 3, kr1 = c1 >> 3;
  const int kg0 = ((c0 & 7) ^ (kr0 & 7)) * 8;
  const int kg1 = ((c1 & 7) ^ (kr1 & 7)) * 8;
  const int cpA = (qd ^ (lm & 7)) * 8;
  const int cpB = cpA ^ 32;

  auto stage = [&](int buf, int k0) {
    __bf16* Kd = Ks + buf * 4096;
    __bf16* Vd = Vs + buf * 4096;
    gld_lds16(Kb + (size_t)(k0 + kr0) * 64 + kg0, &Kd[c0 * 8]);
    gld_lds16(Kb + (size_t)(k0 + kr1) * 64 + kg1, &Kd[c1 * 8]);
    gld_lds16(Vb + (size_t)kr0 * S_LEN + k0 + kg0, &Vd[c0 * 8]);
    gld_lds16(Vb + (size_t)kr1 * S_LEN + k0 + kg1, &Vd[c1 * 8]);
  };

  const float SC2 = 0.125f * 1.44269504089f;   // 1/sqrt(64) * log2(e)
  const float OFF = 12.0f;                     // fixed exponent offset (cancels in norm)
  f32x4 zero = {0.f, 0.f, 0.f, 0.f};
  float l[4] = {0.f, 0.f, 0.f, 0.f};
  f32x4 o[4];
  #pragma unroll
  for (int jb = 0; jb < 4; jb++) o[jb] = zero;

  stage(0, 0);

  const int rowg = row0 + qd * 4;
  const int pxor = qd * 4;

  for (int kt = 0; kt <= qt; ++kt) {
    const int cur = kt & 1;
    __syncthreads();                 // buf[cur] staged; buf[cur^1] free
    if (kt < qt) stage(cur ^ 1, (kt + 1) * 64);

    const __bf16* Kc = Ks + cur * 4096;
    const __bf16* Vc = Vs + cur * 4096;
    const int k0 = kt * 64;

    float p[4][4];
    const bool diag = (kt == qt);
    #pragma unroll
    for (int kb = 0; kb < 4; kb++) {
      const int krow = (kb * 16 + lm) * 64;
      const bf16x8 bk0 = *(const bf16x8*)&Kc[krow + cpA];
      const bf16x8 bk1 = *(const bf16x8*)&Kc[krow + cpB];
      f32x4 sc = zero;
      sc = __builtin_amdgcn_mfma_f32_16x16x32_bf16(aq0, bk0, sc, 0, 0, 0);
      sc = __builtin_amdgcn_mfma_f32_16x16x32_bf16(aq1, bk1, sc, 0, 0, 0);
      if (diag) {
        const int colg = k0 + kb * 16 + lm;
        #pragma unroll
        for (int r = 0; r < 4; r++) {
          const float e = fast_exp2(fmaf(sc[r], SC2, -OFF));
          p[kb][r] = (colg <= rowg + r) ? e : 0.f;
          l[r] += p[kb][r];
        }
      } else {
        #pragma unroll
        for (int r = 0; r < 4; r++) {
          p[kb][r] = fast_exp2(fmaf(sc[r], SC2, -OFF));
          l[r] += p[kb][r];
        }
      }
    }

    // P: C-layout -> LDS (stride-64, XOR-chunk swizzled) -> A-layout frags
    #pragma unroll
    for (int kb = 0; kb < 4; kb++) {
      const int cb = kb * 2 + (lm >> 3), wi = lm & 7;
      #pragma unroll
      for (int r = 0; r < 4; r++) {
        const int prow = pxor + r;
        Pw[prow * 64 + ((cb ^ (prow & 7)) << 3) + wi] = (__bf16)p[kb][r];
      }
    }

    const bf16x8 ap0 = *(const bf16x8*)&Pw[lm * 64 + cpA];
    const bf16x8 ap1 = *(const bf16x8*)&Pw[lm * 64 + cpB];
    #pragma unroll
    for (int jb = 0; jb < 4; jb++) {
      const int vrow = (jb * 16 + lm) * 64;
      const bf16x8 bv0 = *(const bf16x8*)&Vc[vrow + cpA];
      const bf16x8 bv1 = *(const bf16x8*)&Vc[vrow + cpB];
      o[jb] = __builtin_amdgcn_mfma_f32_16x16x32_bf16(ap1, bv1,
              __builtin_amdgcn_mfma_f32_16x16x32_bf16(ap0, bv0, o[jb], 0, 0, 0), 0, 0, 0);
    }
  }

  const int b = bh >> 4, h = bh & 15;
  #pragma unroll
  for (int r = 0; r < 4; r++) {
    float lr = l[r];
    #pragma unroll
    for (int off = 8; off; off >>= 1) lr += __shfl_xor(lr, off);
    const float inv = 1.0f / lr;
    const size_t base = ((size_t)(b * S_LEN + rowg + r)) * D_DIM + h * 64;
    #pragma unroll
    for (int jb = 0; jb < 4; jb++)
      Ob[base + jb * 16 + lm] = (__bf16)(o[jb][r] * inv);
  }
}

extern "C" void kernel_launch(void* const* d_in, const int* in_sizes, int n_in,
                              void* d_out, int out_size, void* d_ws, size_t ws_size,
                              hipStream_t stream)
{
  (void)in_sizes; (void)n_in; (void)out_size; (void)ws_size;
  const float* x    = (const float*)d_in[0];
  const float* WQ   = (const float*)d_in[1];
  const float* WK   = (const float*)d_in[2];
  const float* WV   = (const float*)d_in[3];
  const float* WO   = (const float*)d_in[4];
  const float* gain = (const float*)d_in[5];
  const int* positions = (const int*)d_in[6];
  const int* theta     = (const int*)d_in[7];
  float* out = (float*)d_out;

  char* ws = (char*)d_ws;
  const size_t MB = 1024 * 1024;
  __bf16* xb  = (__bf16*)(ws + 0);        //  8 MB
  __bf16* WQb = (__bf16*)(ws + 8  * MB);  //  2 MB
  __bf16* WKb = (__bf16*)(ws + 10 * MB);  //  2 MB
  __bf16* WVb = (__bf16*)(ws + 12 * MB);  //  2 MB
  __bf16* WOb = (__bf16*)(ws + 14 * MB);  //  2 MB
  __bf16* Qfb = (__bf16*)(ws + 16 * MB);  //  8 MB  Q pre-norm bf16 [4096][1024]
  __bf16* Kfb = (__bf16*)(ws + 24 * MB);  //  8 MB
  __bf16* Vt  = (__bf16*)(ws + 32 * MB);  //  8 MB  [bh][64][s]  (direct from GEMM)
  __bf16* Qh  = (__bf16*)(ws + 40 * MB);  //  8 MB  [bh][s][64]
  __bf16* Kh  = (__bf16*)(ws + 48 * MB);  //  8 MB
  __bf16* Ob  = (__bf16*)(ws + 56 * MB);  //  8 MB  [b][s][1024]

  cast_all<<<1024, 256, 0, stream>>>(x, WQ, WK, WV, WO, xb, WQb, WKb, WVb, WOb);
  gemm_qkv<<<1536, 256, 0, stream>>>(xb, WQb, WKb, WVb, Qfb, Kfb, Vt);
  norm_rope<<<4096, 256, 0, stream>>>(Qfb, Kfb, gain, positions, theta, Qh, Kh);
  attn_fwd<<<1024, 256, 0, stream>>>(Qh, Kh, Vt, Ob);
  gemm_out64<<<512, 256, 0, stream>>>(Ob, WOb, out);
}